// Round 1
// baseline (1101.851 us; speedup 1.0000x reference)
//
#include <hip/hip_runtime.h>
#include <math.h>

#define NN 50000
#define NE 800000
#define ET (NE + NN)
#define NG 64
#define H 4

// ---------------- CSR build ----------------

__global__ __launch_bounds__(256) void k_count(const int* __restrict__ ei, int* __restrict__ deg) {
    int e = blockIdx.x * 256 + threadIdx.x;
    if (e >= ET) return;
    int d = (e < NE) ? ei[NE + e] : (e - NE);
    atomicAdd(&deg[d], 1);
}

__global__ __launch_bounds__(256) void k_hist(const int* __restrict__ batch, int* __restrict__ cnt) {
    int i = blockIdx.x * 256 + threadIdx.x;
    if (i < NN) atomicAdd(&cnt[batch[i]], 1);
}

__global__ __launch_bounds__(1024) void k_scan(const int* __restrict__ deg, int* __restrict__ rowptr,
                                               int* __restrict__ cursor) {
    __shared__ int lds[1024];
    int tid = threadIdx.x;
    int running = 0;
    for (int base = 0; base < NN; base += 1024) {
        int i = base + tid;
        int v = (i < NN) ? deg[i] : 0;
        lds[tid] = v;
        __syncthreads();
        for (int off = 1; off < 1024; off <<= 1) {
            int t = (tid >= off) ? lds[tid - off] : 0;
            __syncthreads();
            lds[tid] += t;
            __syncthreads();
        }
        int incl = lds[tid];
        int total = lds[1023];
        if (i < NN) { int p = running + incl - v; rowptr[i] = p; cursor[i] = p; }
        __syncthreads();
        running += total;
    }
    if (tid == 0) rowptr[NN] = running;
}

__global__ __launch_bounds__(256) void k_scatter(const int* __restrict__ ei, int* __restrict__ cursor,
                                                 int* __restrict__ colsrc) {
    int e = blockIdx.x * 256 + threadIdx.x;
    if (e >= ET) return;
    int s, d;
    if (e < NE) { s = ei[e]; d = ei[NE + e]; } else { s = e - NE; d = s; }
    int pos = atomicAdd(&cursor[d], 1);
    colsrc[pos] = s;
}

// ---------------- fp32 tiled GEMM: O[NN,M] = A[NN,K] @ W[K,M]  (K multiple of 64) ----------------

__global__ __launch_bounds__(256) void k_gemm(const float* __restrict__ A, const float* __restrict__ W,
                                              float* __restrict__ O, int K, int M) {
    __shared__ float As[64][65];
    __shared__ float Ws[64][65];
    int row0 = blockIdx.x * 64, col0 = blockIdx.y * 64;
    int tid = threadIdx.x;
    int tx = tid & 15, ty = tid >> 4;
    float acc[4][4] = {{0.f}};
    for (int k0 = 0; k0 < K; k0 += 64) {
        for (int i = tid; i < 4096; i += 256) {
            int r = i >> 6, kk = i & 63;
            int gr = row0 + r;
            As[r][kk] = (gr < NN) ? A[(size_t)gr * K + k0 + kk] : 0.f;
        }
        for (int i = tid; i < 4096; i += 256) {
            int kk = i >> 6, cc = i & 63;
            int gc = col0 + cc;
            Ws[kk][cc] = (gc < M) ? W[(size_t)(k0 + kk) * M + gc] : 0.f;
        }
        __syncthreads();
#pragma unroll 8
        for (int kk = 0; kk < 64; ++kk) {
            float a[4], b[4];
#pragma unroll
            for (int i = 0; i < 4; ++i) a[i] = As[ty * 4 + i][kk];
#pragma unroll
            for (int j = 0; j < 4; ++j) b[j] = Ws[kk][tx * 4 + j];
#pragma unroll
            for (int i = 0; i < 4; ++i)
#pragma unroll
                for (int j = 0; j < 4; ++j) acc[i][j] += a[i] * b[j];
        }
        __syncthreads();
    }
#pragma unroll
    for (int i = 0; i < 4; ++i) {
        int r = row0 + ty * 4 + i;
        if (r >= NN) continue;
#pragma unroll
        for (int j = 0; j < 4; ++j) {
            int c = col0 + tx * 4 + j;
            if (c < M) O[(size_t)r * M + c] = acc[i][j];
        }
    }
}

// ---------------- GATv2 attention: one thread per (node, head), online softmax over CSR ----------------
// out may alias xr: each thread reads only its own xr row (cached to regs first) and gathers only from xl.

template <int C, bool CONCAT>
__global__ __launch_bounds__(256, 2) void k_attn(const float* __restrict__ xl, const float* __restrict__ xr,
                                                 const int* __restrict__ rowptr, const int* __restrict__ colsrc,
                                                 const float* __restrict__ att, const float* __restrict__ bias,
                                                 float* __restrict__ out) {
    int t = blockIdx.x * 256 + threadIdx.x;
    if (t >= NN * H) return;
    int node = t >> 2, h = t & 3;
    float xrr[C], attv[C], acc[C];
    {
        const float4* p = (const float4*)(xr + (size_t)node * (H * C) + h * C);
        const float4* q = (const float4*)(att + h * C);
#pragma unroll
        for (int c4 = 0; c4 < C / 4; ++c4) {
            float4 v = p[c4];
            xrr[4 * c4 + 0] = v.x; xrr[4 * c4 + 1] = v.y; xrr[4 * c4 + 2] = v.z; xrr[4 * c4 + 3] = v.w;
            float4 w = q[c4];
            attv[4 * c4 + 0] = w.x; attv[4 * c4 + 1] = w.y; attv[4 * c4 + 2] = w.z; attv[4 * c4 + 3] = w.w;
        }
    }
#pragma unroll
    for (int c = 0; c < C; ++c) acc[c] = 0.f;
    float m = -INFINITY, denom = 0.f;
    int beg = rowptr[node], end = rowptr[node + 1];
    for (int idx = beg; idx < end; ++idx) {
        int s = colsrc[idx];
        const float4* p = (const float4*)(xl + (size_t)s * (H * C) + h * C);
        float xv[C];
#pragma unroll
        for (int c4 = 0; c4 < C / 4; ++c4) {
            float4 v = p[c4];
            xv[4 * c4 + 0] = v.x; xv[4 * c4 + 1] = v.y; xv[4 * c4 + 2] = v.z; xv[4 * c4 + 3] = v.w;
        }
        float score = 0.f;
#pragma unroll
        for (int c = 0; c < C; ++c) {
            float z = xv[c] + xrr[c];
            z = (z > 0.f) ? z : 0.2f * z;   // leaky_relu, slope 0.2
            score += attv[c] * z;
        }
        float mn = fmaxf(m, score);
        float es = __expf(m - mn);      // m=-inf first iter -> 0
        float w = __expf(score - mn);
        denom = denom * es + w;
#pragma unroll
        for (int c = 0; c < C; ++c) acc[c] = acc[c] * es + w * xv[c];
        m = mn;
    }
    float inv = 1.f / denom;
    float* op = out + (size_t)node * (H * C) + h * C;
#pragma unroll
    for (int c = 0; c < C; c += 4) {
        float4 v;
        v.x = acc[c + 0] * inv + (CONCAT ? bias[h * C + c + 0] : 0.f);
        v.y = acc[c + 1] * inv + (CONCAT ? bias[h * C + c + 1] : 0.f);
        v.z = acc[c + 2] * inv + (CONCAT ? bias[h * C + c + 2] : 0.f);
        v.w = acc[c + 3] * inv + (CONCAT ? bias[h * C + c + 3] : 0.f);
        *(float4*)(op + c) = v;
    }
}

// ---------------- GraphNorm ----------------
// reduce: per-thread run-length accumulation over sorted batch; flush on graph change.

__global__ __launch_bounds__(256) void k_gnred(const float* __restrict__ h, const int* __restrict__ batch,
                                               float* __restrict__ sum, float* __restrict__ sumsq, int logC) {
    int C = 1 << logC;
    int c = threadIdx.x & (C - 1);
    int row = threadIdx.x >> logC;
    int rows = 256 >> logC;
    int base = blockIdx.x * 256;
    int curg = -1;
    float s = 0.f, ss = 0.f;
    for (int r = row; r < 256; r += rows) {
        int nd = base + r;
        if (nd >= NN) break;
        int g = batch[nd];
        if (g != curg) {
            if (curg >= 0) { atomicAdd(&sum[curg * C + c], s); atomicAdd(&sumsq[curg * C + c], ss); }
            curg = g; s = 0.f; ss = 0.f;
        }
        float x = h[(size_t)nd * C + c];
        s += x; ss += x * x;
    }
    if (curg >= 0) { atomicAdd(&sum[curg * C + c], s); atomicAdd(&sumsq[curg * C + c], ss); }
}

// var(out) = E[x^2] - (2s - s^2) mu^2  where out = x - mu*s
__global__ __launch_bounds__(256) void k_gnnorm(float* __restrict__ h, const int* __restrict__ batch,
                                                const float* __restrict__ sum, const float* __restrict__ sumsq,
                                                const int* __restrict__ cnt, const float* __restrict__ w,
                                                const float* __restrict__ b, const float* __restrict__ ms,
                                                int logC) {
    int C = 1 << logC;
    int i = blockIdx.x * 256 + threadIdx.x;
    if (i >= NN * C) return;
    int nd = i >> logC, c = i & (C - 1);
    int g = batch[nd];
    float cg = fmaxf((float)cnt[g], 1.f);
    float mu = sum[g * C + c] / cg;
    float ex2 = sumsq[g * C + c] / cg;
    float s_ = ms[c];
    float var = ex2 - (2.f * s_ - s_ * s_) * mu * mu;
    float y = (h[i] - mu * s_) * rsqrtf(var + 1e-5f) * w[c] + b[c];
    h[i] = fmaxf(y, 0.f);   // fused ReLU
}

// ---------------- layer-3 head mean + bias ----------------

__global__ __launch_bounds__(256) void k_headmean(const float* __restrict__ tmp, const float* __restrict__ b3,
                                                  float* __restrict__ out) {
    int i = blockIdx.x * 256 + threadIdx.x;
    if (i >= NN * 8) return;
    int nd = i >> 3, c = i & 7;
    const float* p = tmp + (size_t)nd * 32 + c;
    out[i] = 0.25f * (p[0] + p[8] + p[16] + p[24]) + b3[c];
}

// ---------------- pool mean + linear head ----------------

__global__ __launch_bounds__(512) void k_final(const float* __restrict__ pool, const int* __restrict__ cnt,
                                               const float* __restrict__ lw, const float* __restrict__ lb,
                                               float* __restrict__ outp) {
    __shared__ float feat[512];
    int t = threadIdx.x;
    int g = t >> 3;
    float f = pool[t] / fmaxf((float)cnt[g], 1.f);
    feat[t] = f;
    outp[256 + t] = f;          // features: d_out[256 .. 768)
    __syncthreads();
    if (t < 256) {
        int g2 = t >> 2, o = t & 3;
        float a = lb[o];
#pragma unroll
        for (int cc = 0; cc < 8; ++cc) a += feat[g2 * 8 + cc] * lw[cc * 4 + o];
        outp[t] = a;            // logits: d_out[0 .. 256)
    }
}

// ---------------- host ----------------

extern "C" void kernel_launch(void* const* d_in, const int* in_sizes, int n_in,
                              void* d_out, int out_size, void* d_ws, size_t ws_size,
                              hipStream_t stream) {
    const float* x    = (const float*)d_in[0];
    const int*   ei   = (const int*)d_in[1];
    const int*   batch= (const int*)d_in[2];
    const float *w_l1 = (const float*)d_in[3],  *w_r1 = (const float*)d_in[4];
    const float *att1 = (const float*)d_in[5],  *b1   = (const float*)d_in[6];
    const float *gn1w = (const float*)d_in[7],  *gn1b = (const float*)d_in[8],  *gn1s = (const float*)d_in[9];
    const float *w_l2 = (const float*)d_in[10], *w_r2 = (const float*)d_in[11];
    const float *att2 = (const float*)d_in[12], *b2   = (const float*)d_in[13];
    const float *gn2w = (const float*)d_in[14], *gn2b = (const float*)d_in[15], *gn2s = (const float*)d_in[16];
    const float *w_l3 = (const float*)d_in[17], *w_r3 = (const float*)d_in[18];
    const float *att3 = (const float*)d_in[19], *b3   = (const float*)d_in[20];
    const float *gn3w = (const float*)d_in[21], *gn3b = (const float*)d_in[22], *gn3s = (const float*)d_in[23];
    const float *lw   = (const float*)d_in[24], *lb   = (const float*)d_in[25];

    char* ws = (char*)d_ws;
    size_t off = 0;
    auto alloc = [&](size_t bytes) -> void* {
        void* p = ws + off;
        off += (bytes + 255) & ~(size_t)255;
        return p;
    };
    float* A  = (float*)alloc((size_t)NN * 128 * 4);   // xl scratch
    float* B  = (float*)alloc((size_t)NN * 128 * 4);   // xr / layer-out scratch
    float* Cb = (float*)alloc((size_t)NN * 64 * 4);    // h2 scratch
    int* rowptr = (int*)alloc((size_t)(NN + 1) * 4);
    int* cursor = (int*)alloc((size_t)NN * 4);
    int* colsrc = (int*)alloc((size_t)ET * 4);
    char* zbase = ws + off;                            // everything below gets one memset
    int*   deg  = (int*)alloc((size_t)NN * 4);
    int*   cnt  = (int*)alloc((size_t)NG * 4);
    float* sum1 = (float*)alloc((size_t)NG * 128 * 4);
    float* sq1  = (float*)alloc((size_t)NG * 128 * 4);
    float* sum2 = (float*)alloc((size_t)NG * 64 * 4);
    float* sq2  = (float*)alloc((size_t)NG * 64 * 4);
    float* sum3 = (float*)alloc((size_t)NG * 8 * 4);
    float* sq3  = (float*)alloc((size_t)NG * 8 * 4);
    float* pool = (float*)alloc((size_t)NG * 8 * 4);
    size_t zbytes = (size_t)((ws + off) - zbase);
    hipMemsetAsync(zbase, 0, zbytes, stream);

    int gE = (ET + 255) / 256;
    k_count<<<gE, 256, 0, stream>>>(ei, deg);
    k_hist<<<(NN + 255) / 256, 256, 0, stream>>>(batch, cnt);
    k_scan<<<1, 1024, 0, stream>>>(deg, rowptr, cursor);
    k_scatter<<<gE, 256, 0, stream>>>(ei, cursor, colsrc);

    int gR = (NN + 63) / 64;          // 782 row-blocks
    int gA = (NN * H + 255) / 256;    // attention grid
    int gN = (NN + 255) / 256;        // gn-reduce grid

    // ---- layer 1: 128 -> 4x32 concat -> 128
    k_gemm<<<dim3(gR, 2), 256, 0, stream>>>(x, w_l1, A, 128, 128);
    k_gemm<<<dim3(gR, 2), 256, 0, stream>>>(x, w_r1, B, 128, 128);
    k_attn<32, true><<<gA, 256, 0, stream>>>(A, B, rowptr, colsrc, att1, b1, B);
    k_gnred<<<gN, 256, 0, stream>>>(B, batch, sum1, sq1, 7);
    k_gnnorm<<<(NN * 128 + 255) / 256, 256, 0, stream>>>(B, batch, sum1, sq1, cnt, gn1w, gn1b, gn1s, 7);

    // ---- layer 2: 128 -> 4x16 concat -> 64
    k_gemm<<<dim3(gR, 1), 256, 0, stream>>>(B, w_l2, A, 128, 64);
    k_gemm<<<dim3(gR, 1), 256, 0, stream>>>(B, w_r2, Cb, 128, 64);
    k_attn<16, true><<<gA, 256, 0, stream>>>(A, Cb, rowptr, colsrc, att2, b2, Cb);
    k_gnred<<<gN, 256, 0, stream>>>(Cb, batch, sum2, sq2, 6);
    k_gnnorm<<<(NN * 64 + 255) / 256, 256, 0, stream>>>(Cb, batch, sum2, sq2, cnt, gn2w, gn2b, gn2s, 6);

    // ---- layer 3: 64 -> 4x8 mean -> 8
    k_gemm<<<dim3(gR, 1), 256, 0, stream>>>(Cb, w_l3, A, 64, 32);
    k_gemm<<<dim3(gR, 1), 256, 0, stream>>>(Cb, w_r3, B, 64, 32);
    k_attn<8, false><<<gA, 256, 0, stream>>>(A, B, rowptr, colsrc, att3, nullptr, B);
    k_headmean<<<(NN * 8 + 255) / 256, 256, 0, stream>>>(B, b3, A);
    k_gnred<<<gN, 256, 0, stream>>>(A, batch, sum3, sq3, 3);
    k_gnnorm<<<(NN * 8 + 255) / 256, 256, 0, stream>>>(A, batch, sum3, sq3, cnt, gn3w, gn3b, gn3s, 3);

    // ---- global mean pool + linear
    k_gnred<<<gN, 256, 0, stream>>>(A, batch, pool, sq3, 3);  // sq3 as throwaway sumsq
    k_final<<<1, 512, 0, stream>>>(pool, cnt, lw, lb, (float*)d_out);
}

// Round 2
// 876.622 us; speedup vs baseline: 1.2569x; 1.2569x over previous
//
#include <hip/hip_runtime.h>
#include <math.h>

#define NN 50000
#define NE 800000
#define ET (NE + NN)
#define NG 64
#define H 4

// ---------------- CSR build ----------------

__global__ __launch_bounds__(256) void k_count(const int* __restrict__ ei, int* __restrict__ deg) {
    int e = blockIdx.x * 256 + threadIdx.x;
    if (e >= ET) return;
    int d = (e < NE) ? ei[NE + e] : (e - NE);
    atomicAdd(&deg[d], 1);
}

// batch is sorted: find graph boundaries without atomics.
// bpos[g] = first node index with batch[i] >= g; bpos[NG] = NN.
__global__ __launch_bounds__(256) void k_bounds(const int* __restrict__ batch, int* __restrict__ bpos) {
    int i = blockIdx.x * 256 + threadIdx.x;
    if (i >= NN) return;
    int cur = batch[i];
    int prev = (i == 0) ? -1 : batch[i - 1];
    for (int g = prev + 1; g <= cur; ++g) bpos[g] = i;
    if (i == NN - 1)
        for (int g = cur + 1; g <= NG; ++g) bpos[g] = NN;
}

__global__ __launch_bounds__(64) void k_cnt(const int* __restrict__ bpos, int* __restrict__ cnt) {
    int g = threadIdx.x;
    if (g < NG) cnt[g] = bpos[g + 1] - bpos[g];
}

__global__ __launch_bounds__(1024) void k_scan(const int* __restrict__ deg, int* __restrict__ rowptr,
                                               int* __restrict__ cursor) {
    __shared__ int lds[1024];
    int tid = threadIdx.x;
    int running = 0;
    for (int base = 0; base < NN; base += 1024) {
        int i = base + tid;
        int v = (i < NN) ? deg[i] : 0;
        lds[tid] = v;
        __syncthreads();
        for (int off = 1; off < 1024; off <<= 1) {
            int t = (tid >= off) ? lds[tid - off] : 0;
            __syncthreads();
            lds[tid] += t;
            __syncthreads();
        }
        int incl = lds[tid];
        int total = lds[1023];
        if (i < NN) { int p = running + incl - v; rowptr[i] = p; cursor[i] = p; }
        __syncthreads();
        running += total;
    }
    if (tid == 0) rowptr[NN] = running;
}

__global__ __launch_bounds__(256) void k_scatter(const int* __restrict__ ei, int* __restrict__ cursor,
                                                 int* __restrict__ colsrc) {
    int e = blockIdx.x * 256 + threadIdx.x;
    if (e >= ET) return;
    int s, d;
    if (e < NE) { s = ei[e]; d = ei[NE + e]; } else { s = e - NE; d = s; }
    int pos = atomicAdd(&cursor[d], 1);
    colsrc[pos] = s;
}

// ---------------- fp32 tiled GEMM: O[NN,M] = A[NN,K] @ W[K,M]  (K multiple of 64) ----------------

__global__ __launch_bounds__(256) void k_gemm(const float* __restrict__ A, const float* __restrict__ W,
                                              float* __restrict__ O, int K, int M) {
    __shared__ float As[64][65];
    __shared__ float Ws[64][65];
    int row0 = blockIdx.x * 64, col0 = blockIdx.y * 64;
    int tid = threadIdx.x;
    int tx = tid & 15, ty = tid >> 4;
    float acc[4][4] = {{0.f}};
    for (int k0 = 0; k0 < K; k0 += 64) {
        for (int i = tid; i < 4096; i += 256) {
            int r = i >> 6, kk = i & 63;
            int gr = row0 + r;
            As[r][kk] = (gr < NN) ? A[(size_t)gr * K + k0 + kk] : 0.f;
        }
        for (int i = tid; i < 4096; i += 256) {
            int kk = i >> 6, cc = i & 63;
            int gc = col0 + cc;
            Ws[kk][cc] = (gc < M) ? W[(size_t)(k0 + kk) * M + gc] : 0.f;
        }
        __syncthreads();
#pragma unroll 8
        for (int kk = 0; kk < 64; ++kk) {
            float a[4], b[4];
#pragma unroll
            for (int i = 0; i < 4; ++i) a[i] = As[ty * 4 + i][kk];
#pragma unroll
            for (int j = 0; j < 4; ++j) b[j] = Ws[kk][tx * 4 + j];
#pragma unroll
            for (int i = 0; i < 4; ++i)
#pragma unroll
                for (int j = 0; j < 4; ++j) acc[i][j] += a[i] * b[j];
        }
        __syncthreads();
    }
#pragma unroll
    for (int i = 0; i < 4; ++i) {
        int r = row0 + ty * 4 + i;
        if (r >= NN) continue;
#pragma unroll
        for (int j = 0; j < 4; ++j) {
            int c = col0 + tx * 4 + j;
            if (c < M) O[(size_t)r * M + c] = acc[i][j];
        }
    }
}

// ---------------- GATv2 attention: one thread per (node, head), online softmax over CSR ----------------
// out may alias xr: each thread reads only its own xr row (cached to regs first) and gathers only from xl.

template <int C, bool CONCAT>
__global__ __launch_bounds__(256, 2) void k_attn(const float* __restrict__ xl, const float* __restrict__ xr,
                                                 const int* __restrict__ rowptr, const int* __restrict__ colsrc,
                                                 const float* __restrict__ att, const float* __restrict__ bias,
                                                 float* __restrict__ out) {
    int t = blockIdx.x * 256 + threadIdx.x;
    if (t >= NN * H) return;
    int node = t >> 2, h = t & 3;
    float xrr[C], attv[C], acc[C];
    {
        const float4* p = (const float4*)(xr + (size_t)node * (H * C) + h * C);
        const float4* q = (const float4*)(att + h * C);
#pragma unroll
        for (int c4 = 0; c4 < C / 4; ++c4) {
            float4 v = p[c4];
            xrr[4 * c4 + 0] = v.x; xrr[4 * c4 + 1] = v.y; xrr[4 * c4 + 2] = v.z; xrr[4 * c4 + 3] = v.w;
            float4 w = q[c4];
            attv[4 * c4 + 0] = w.x; attv[4 * c4 + 1] = w.y; attv[4 * c4 + 2] = w.z; attv[4 * c4 + 3] = w.w;
        }
    }
#pragma unroll
    for (int c = 0; c < C; ++c) acc[c] = 0.f;
    float m = -INFINITY, denom = 0.f;
    int beg = rowptr[node], end = rowptr[node + 1];
    for (int idx = beg; idx < end; ++idx) {
        int s = colsrc[idx];
        const float4* p = (const float4*)(xl + (size_t)s * (H * C) + h * C);
        float xv[C];
#pragma unroll
        for (int c4 = 0; c4 < C / 4; ++c4) {
            float4 v = p[c4];
            xv[4 * c4 + 0] = v.x; xv[4 * c4 + 1] = v.y; xv[4 * c4 + 2] = v.z; xv[4 * c4 + 3] = v.w;
        }
        float score = 0.f;
#pragma unroll
        for (int c = 0; c < C; ++c) {
            float z = xv[c] + xrr[c];
            z = (z > 0.f) ? z : 0.2f * z;   // leaky_relu, slope 0.2
            score += attv[c] * z;
        }
        float mn = fmaxf(m, score);
        float es = __expf(m - mn);      // m=-inf first iter -> 0
        float w = __expf(score - mn);
        denom = denom * es + w;
#pragma unroll
        for (int c = 0; c < C; ++c) acc[c] = acc[c] * es + w * xv[c];
        m = mn;
    }
    float inv = 1.f / denom;
    float* op = out + (size_t)node * (H * C) + h * C;
#pragma unroll
    for (int c = 0; c < C; c += 4) {
        float4 v;
        v.x = acc[c + 0] * inv + (CONCAT ? bias[h * C + c + 0] : 0.f);
        v.y = acc[c + 1] * inv + (CONCAT ? bias[h * C + c + 1] : 0.f);
        v.z = acc[c + 2] * inv + (CONCAT ? bias[h * C + c + 2] : 0.f);
        v.w = acc[c + 3] * inv + (CONCAT ? bias[h * C + c + 3] : 0.f);
        *(float4*)(op + c) = v;
    }
}

// ---------------- GraphNorm ----------------
// reduce: per-thread run-length accumulation over sorted batch; flush on graph change.

__global__ __launch_bounds__(256) void k_gnred(const float* __restrict__ h, const int* __restrict__ batch,
                                               float* __restrict__ sum, float* __restrict__ sumsq, int logC) {
    int C = 1 << logC;
    int c = threadIdx.x & (C - 1);
    int row = threadIdx.x >> logC;
    int rows = 256 >> logC;
    int base = blockIdx.x * 256;
    int curg = -1;
    float s = 0.f, ss = 0.f;
    for (int r = row; r < 256; r += rows) {
        int nd = base + r;
        if (nd >= NN) break;
        int g = batch[nd];
        if (g != curg) {
            if (curg >= 0) { atomicAdd(&sum[curg * C + c], s); atomicAdd(&sumsq[curg * C + c], ss); }
            curg = g; s = 0.f; ss = 0.f;
        }
        float x = h[(size_t)nd * C + c];
        s += x; ss += x * x;
    }
    if (curg >= 0) { atomicAdd(&sum[curg * C + c], s); atomicAdd(&sumsq[curg * C + c], ss); }
}

// var(out) = E[x^2] - (2s - s^2) mu^2  where out = x - mu*s
__global__ __launch_bounds__(256) void k_gnnorm(float* __restrict__ h, const int* __restrict__ batch,
                                                const float* __restrict__ sum, const float* __restrict__ sumsq,
                                                const int* __restrict__ cnt, const float* __restrict__ w,
                                                const float* __restrict__ b, const float* __restrict__ ms,
                                                int logC) {
    int C = 1 << logC;
    int i = blockIdx.x * 256 + threadIdx.x;
    if (i >= NN * C) return;
    int nd = i >> logC, c = i & (C - 1);
    int g = batch[nd];
    float cg = fmaxf((float)cnt[g], 1.f);
    float mu = sum[g * C + c] / cg;
    float ex2 = sumsq[g * C + c] / cg;
    float s_ = ms[c];
    float var = ex2 - (2.f * s_ - s_ * s_) * mu * mu;
    float y = (h[i] - mu * s_) * rsqrtf(var + 1e-5f) * w[c] + b[c];
    h[i] = fmaxf(y, 0.f);   // fused ReLU
}

// ---------------- layer-3 head mean + bias ----------------

__global__ __launch_bounds__(256) void k_headmean(const float* __restrict__ tmp, const float* __restrict__ b3,
                                                  float* __restrict__ out) {
    int i = blockIdx.x * 256 + threadIdx.x;
    if (i >= NN * 8) return;
    int nd = i >> 3, c = i & 7;
    const float* p = tmp + (size_t)nd * 32 + c;
    out[i] = 0.25f * (p[0] + p[8] + p[16] + p[24]) + b3[c];
}

// ---------------- pool mean + linear head ----------------

__global__ __launch_bounds__(512) void k_final(const float* __restrict__ pool, const int* __restrict__ cnt,
                                               const float* __restrict__ lw, const float* __restrict__ lb,
                                               float* __restrict__ outp) {
    __shared__ float feat[512];
    int t = threadIdx.x;
    int g = t >> 3;
    float f = pool[t] / fmaxf((float)cnt[g], 1.f);
    feat[t] = f;
    outp[256 + t] = f;          // features: d_out[256 .. 768)
    __syncthreads();
    if (t < 256) {
        int g2 = t >> 2, o = t & 3;
        float a = lb[o];
#pragma unroll
        for (int cc = 0; cc < 8; ++cc) a += feat[g2 * 8 + cc] * lw[cc * 4 + o];
        outp[t] = a;            // logits: d_out[0 .. 256)
    }
}

// ---------------- host ----------------

extern "C" void kernel_launch(void* const* d_in, const int* in_sizes, int n_in,
                              void* d_out, int out_size, void* d_ws, size_t ws_size,
                              hipStream_t stream) {
    const float* x    = (const float*)d_in[0];
    const int*   ei   = (const int*)d_in[1];
    const int*   batch= (const int*)d_in[2];
    const float *w_l1 = (const float*)d_in[3],  *w_r1 = (const float*)d_in[4];
    const float *att1 = (const float*)d_in[5],  *b1   = (const float*)d_in[6];
    const float *gn1w = (const float*)d_in[7],  *gn1b = (const float*)d_in[8],  *gn1s = (const float*)d_in[9];
    const float *w_l2 = (const float*)d_in[10], *w_r2 = (const float*)d_in[11];
    const float *att2 = (const float*)d_in[12], *b2   = (const float*)d_in[13];
    const float *gn2w = (const float*)d_in[14], *gn2b = (const float*)d_in[15], *gn2s = (const float*)d_in[16];
    const float *w_l3 = (const float*)d_in[17], *w_r3 = (const float*)d_in[18];
    const float *att3 = (const float*)d_in[19], *b3   = (const float*)d_in[20];
    const float *gn3w = (const float*)d_in[21], *gn3b = (const float*)d_in[22], *gn3s = (const float*)d_in[23];
    const float *lw   = (const float*)d_in[24], *lb   = (const float*)d_in[25];

    char* ws = (char*)d_ws;
    size_t off = 0;
    auto alloc = [&](size_t bytes) -> void* {
        void* p = ws + off;
        off += (bytes + 255) & ~(size_t)255;
        return p;
    };
    float* A  = (float*)alloc((size_t)NN * 128 * 4);   // xl scratch
    float* B  = (float*)alloc((size_t)NN * 128 * 4);   // xr / layer-out scratch
    float* Cb = (float*)alloc((size_t)NN * 64 * 4);    // h2 scratch
    int* rowptr = (int*)alloc((size_t)(NN + 1) * 4);
    int* cursor = (int*)alloc((size_t)NN * 4);
    int* colsrc = (int*)alloc((size_t)ET * 4);
    int* bpos   = (int*)alloc((size_t)(NG + 1) * 4);
    int* cnt    = (int*)alloc((size_t)NG * 4);
    char* zbase = ws + off;                            // everything below gets one memset
    int*   deg  = (int*)alloc((size_t)NN * 4);
    float* sum1 = (float*)alloc((size_t)NG * 128 * 4);
    float* sq1  = (float*)alloc((size_t)NG * 128 * 4);
    float* sum2 = (float*)alloc((size_t)NG * 64 * 4);
    float* sq2  = (float*)alloc((size_t)NG * 64 * 4);
    float* sum3 = (float*)alloc((size_t)NG * 8 * 4);
    float* sq3  = (float*)alloc((size_t)NG * 8 * 4);
    float* pool = (float*)alloc((size_t)NG * 8 * 4);
    size_t zbytes = (size_t)((ws + off) - zbase);
    hipMemsetAsync(zbase, 0, zbytes, stream);

    int gE = (ET + 255) / 256;
    k_count<<<gE, 256, 0, stream>>>(ei, deg);
    k_bounds<<<(NN + 255) / 256, 256, 0, stream>>>(batch, bpos);
    k_cnt<<<1, 64, 0, stream>>>(bpos, cnt);
    k_scan<<<1, 1024, 0, stream>>>(deg, rowptr, cursor);
    k_scatter<<<gE, 256, 0, stream>>>(ei, cursor, colsrc);

    int gR = (NN + 63) / 64;          // 782 row-blocks
    int gA = (NN * H + 255) / 256;    // attention grid
    int gN = (NN + 255) / 256;        // gn-reduce grid

    // ---- layer 1: 128 -> 4x32 concat -> 128
    k_gemm<<<dim3(gR, 2), 256, 0, stream>>>(x, w_l1, A, 128, 128);
    k_gemm<<<dim3(gR, 2), 256, 0, stream>>>(x, w_r1, B, 128, 128);
    k_attn<32, true><<<gA, 256, 0, stream>>>(A, B, rowptr, colsrc, att1, b1, B);
    k_gnred<<<gN, 256, 0, stream>>>(B, batch, sum1, sq1, 7);
    k_gnnorm<<<(NN * 128 + 255) / 256, 256, 0, stream>>>(B, batch, sum1, sq1, cnt, gn1w, gn1b, gn1s, 7);

    // ---- layer 2: 128 -> 4x16 concat -> 64
    k_gemm<<<dim3(gR, 1), 256, 0, stream>>>(B, w_l2, A, 128, 64);
    k_gemm<<<dim3(gR, 1), 256, 0, stream>>>(B, w_r2, Cb, 128, 64);
    k_attn<16, true><<<gA, 256, 0, stream>>>(A, Cb, rowptr, colsrc, att2, b2, Cb);
    k_gnred<<<gN, 256, 0, stream>>>(Cb, batch, sum2, sq2, 6);
    k_gnnorm<<<(NN * 64 + 255) / 256, 256, 0, stream>>>(Cb, batch, sum2, sq2, cnt, gn2w, gn2b, gn2s, 6);

    // ---- layer 3: 64 -> 4x8 mean -> 8
    k_gemm<<<dim3(gR, 1), 256, 0, stream>>>(Cb, w_l3, A, 64, 32);
    k_gemm<<<dim3(gR, 1), 256, 0, stream>>>(Cb, w_r3, B, 64, 32);
    k_attn<8, false><<<gA, 256, 0, stream>>>(A, B, rowptr, colsrc, att3, nullptr, B);
    k_headmean<<<(NN * 8 + 255) / 256, 256, 0, stream>>>(B, b3, A);
    k_gnred<<<gN, 256, 0, stream>>>(A, batch, sum3, sq3, 3);
    k_gnnorm<<<(NN * 8 + 255) / 256, 256, 0, stream>>>(A, batch, sum3, sq3, cnt, gn3w, gn3b, gn3s, 3);

    // ---- global mean pool + linear
    k_gnred<<<gN, 256, 0, stream>>>(A, batch, pool, sq3, 3);  // sq3 as throwaway sumsq
    k_final<<<1, 512, 0, stream>>>(pool, cnt, lw, lb, (float*)d_out);
}

// Round 3
// 719.511 us; speedup vs baseline: 1.5314x; 1.2184x over previous
//
#include <hip/hip_runtime.h>
#include <hip/hip_fp16.h>
#include <math.h>

#define NN 50000
#define NE 800000
#define ET (NE + NN)
#define NG 64
#define H 4
#define NB ((NN + 255) / 256)   // 196 blocks of 256 nodes

// ---------------- CSR build ----------------

__global__ __launch_bounds__(256) void k_count(const int* __restrict__ ei, int* __restrict__ deg) {
    int e = blockIdx.x * 256 + threadIdx.x;
    if (e >= ET) return;
    int d = (e < NE) ? ei[NE + e] : (e - NE);
    atomicAdd(&deg[d], 1);
}

// batch is sorted: graph boundaries without atomics.
__global__ __launch_bounds__(256) void k_bounds(const int* __restrict__ batch, int* __restrict__ bpos) {
    int i = blockIdx.x * 256 + threadIdx.x;
    if (i >= NN) return;
    int cur = batch[i];
    int prev = (i == 0) ? -1 : batch[i - 1];
    for (int g = prev + 1; g <= cur; ++g) bpos[g] = i;
    if (i == NN - 1)
        for (int g = cur + 1; g <= NG; ++g) bpos[g] = NN;
}

__global__ __launch_bounds__(64) void k_cnt(const int* __restrict__ bpos, int* __restrict__ cnt) {
    int g = threadIdx.x;
    if (g < NG) cnt[g] = bpos[g + 1] - bpos[g];
}

// ---- decoupled 3-pass exclusive scan of deg[] -> rowptr/cursor (replaces serial 1-block scan)

__global__ __launch_bounds__(256) void k_blksum(const int* __restrict__ deg, int* __restrict__ bsum) {
    int i = blockIdx.x * 256 + threadIdx.x;
    int v = (i < NN) ? deg[i] : 0;
    for (int off = 32; off; off >>= 1) v += __shfl_down(v, off, 64);
    __shared__ int lds[4];
    int lane = threadIdx.x & 63, wid = threadIdx.x >> 6;
    if (lane == 0) lds[wid] = v;
    __syncthreads();
    if (threadIdx.x == 0) bsum[blockIdx.x] = lds[0] + lds[1] + lds[2] + lds[3];
}

__global__ __launch_bounds__(256) void k_scanb(const int* __restrict__ bsum, int* __restrict__ boff) {
    __shared__ int lds[256];
    int t = threadIdx.x;
    int v = (t < NB) ? bsum[t] : 0;
    lds[t] = v;
    __syncthreads();
    for (int off = 1; off < 256; off <<= 1) {
        int y = (t >= off) ? lds[t - off] : 0;
        __syncthreads();
        lds[t] += y;
        __syncthreads();
    }
    if (t < NB) boff[t] = lds[t] - v;   // exclusive
}

__global__ __launch_bounds__(256) void k_scanc(const int* __restrict__ deg, const int* __restrict__ boff,
                                               int* __restrict__ rowptr, int* __restrict__ cursor) {
    int b = blockIdx.x, t = threadIdx.x;
    int i = b * 256 + t;
    int v = (i < NN) ? deg[i] : 0;
    int lane = t & 63, wid = t >> 6;
    int x = v;
    for (int off = 1; off < 64; off <<= 1) {
        int y = __shfl_up(x, off, 64);
        if (lane >= off) x += y;
    }
    __shared__ int wsum[4];
    if (lane == 63) wsum[wid] = x;
    __syncthreads();
    int base = boff[b];
    for (int w = 0; w < wid; ++w) base += wsum[w];
    int p = base + x - v;   // exclusive prefix for node i
    if (i < NN) { rowptr[i] = p; cursor[i] = p; }
    if (i == NN - 1) rowptr[NN] = p + v;
}

__global__ __launch_bounds__(256) void k_scatter(const int* __restrict__ ei, int* __restrict__ cursor,
                                                 int* __restrict__ colsrc) {
    int e = blockIdx.x * 256 + threadIdx.x;
    if (e >= ET) return;
    int s, d;
    if (e < NE) { s = ei[e]; d = ei[NE + e]; } else { s = e - NE; d = s; }
    int pos = atomicAdd(&cursor[d], 1);
    colsrc[pos] = s;
}

// ---------------- fp32 tiled GEMM: O[NN,M] = A[NN,K] @ W[K,M]  (K,M multiples of 4; K mult of 64)
// OT=float (x_r path) or __half (x_l path, halves attention gather bytes)

template <typename OT>
__global__ __launch_bounds__(256) void k_gemm(const float* __restrict__ A, const float* __restrict__ W,
                                              OT* __restrict__ O, int K, int M) {
    __shared__ float As[64][65];
    __shared__ float Ws[64][65];
    int row0 = blockIdx.x * 64, col0 = blockIdx.y * 64;
    int tid = threadIdx.x;
    int tx = tid & 15, ty = tid >> 4;
    float acc[4][4] = {{0.f}};
    for (int k0 = 0; k0 < K; k0 += 64) {
        for (int i = tid; i < 4096; i += 256) {
            int r = i >> 6, kk = i & 63;
            int gr = row0 + r;
            As[r][kk] = (gr < NN) ? A[(size_t)gr * K + k0 + kk] : 0.f;
        }
        for (int i = tid; i < 4096; i += 256) {
            int kk = i >> 6, cc = i & 63;
            int gc = col0 + cc;
            Ws[kk][cc] = (gc < M) ? W[(size_t)(k0 + kk) * M + gc] : 0.f;
        }
        __syncthreads();
#pragma unroll 8
        for (int kk = 0; kk < 64; ++kk) {
            float a[4], b[4];
#pragma unroll
            for (int i = 0; i < 4; ++i) a[i] = As[ty * 4 + i][kk];
#pragma unroll
            for (int j = 0; j < 4; ++j) b[j] = Ws[kk][tx * 4 + j];
#pragma unroll
            for (int i = 0; i < 4; ++i)
#pragma unroll
                for (int j = 0; j < 4; ++j) acc[i][j] += a[i] * b[j];
        }
        __syncthreads();
    }
    int c0 = col0 + tx * 4;
    if (c0 >= M) return;
#pragma unroll
    for (int i = 0; i < 4; ++i) {
        int r = row0 + ty * 4 + i;
        if (r >= NN) continue;
        if constexpr (__is_same(OT, __half)) {
            __half2 st[2];
            st[0] = __floats2half2_rn(acc[i][0], acc[i][1]);
            st[1] = __floats2half2_rn(acc[i][2], acc[i][3]);
            *(float2*)(O + (size_t)r * M + c0) = *(float2*)st;
        } else {
            float4 v = make_float4(acc[i][0], acc[i][1], acc[i][2], acc[i][3]);
            *(float4*)(O + (size_t)r * M + c0) = v;
        }
    }
}

// ---------------- GATv2 attention: one thread per (node, head), online softmax over CSR ----------------
// xl is fp16 (halved gather bytes); xr/out fp32. out may alias xr.

template <int C>
__device__ __forceinline__ void attn_edge(const float4* __restrict__ raw, const float* __restrict__ xrr,
                                          const float* __restrict__ attv, float& m, float& denom,
                                          float* __restrict__ acc) {
    float xv[C];
#pragma unroll
    for (int i = 0; i < C / 8; ++i) {
        float4 r = raw[i];
        const __half2* hp = (const __half2*)&r;
#pragma unroll
        for (int j = 0; j < 4; ++j) {
            float2 f = __half22float2(hp[j]);
            xv[8 * i + 2 * j] = f.x;
            xv[8 * i + 2 * j + 1] = f.y;
        }
    }
    float score = 0.f;
#pragma unroll
    for (int c = 0; c < C; ++c) {
        float z = xv[c] + xrr[c];
        z = (z > 0.f) ? z : 0.2f * z;   // leaky_relu slope 0.2
        score += attv[c] * z;
    }
    float mn = fmaxf(m, score);
    float es = __expf(m - mn);          // m=-inf first edge -> 0
    float w = __expf(score - mn);
    denom = denom * es + w;
#pragma unroll
    for (int c = 0; c < C; ++c) acc[c] = acc[c] * es + w * xv[c];
    m = mn;
}

template <int C, bool CONCAT>
__global__ __launch_bounds__(256, 2) void k_attn(const __half* __restrict__ xl, const float* __restrict__ xr,
                                                 const int* __restrict__ rowptr, const int* __restrict__ colsrc,
                                                 const float* __restrict__ att, const float* __restrict__ bias,
                                                 float* __restrict__ out) {
    int t = blockIdx.x * 256 + threadIdx.x;
    if (t >= NN * H) return;
    int node = t >> 2, h = t & 3;
    float xrr[C], attv[C], acc[C];
    {
        const float4* p = (const float4*)(xr + (size_t)node * (H * C) + h * C);
        const float4* q = (const float4*)(att + h * C);
#pragma unroll
        for (int c4 = 0; c4 < C / 4; ++c4) {
            float4 v = p[c4];
            xrr[4 * c4 + 0] = v.x; xrr[4 * c4 + 1] = v.y; xrr[4 * c4 + 2] = v.z; xrr[4 * c4 + 3] = v.w;
            float4 w = q[c4];
            attv[4 * c4 + 0] = w.x; attv[4 * c4 + 1] = w.y; attv[4 * c4 + 2] = w.z; attv[4 * c4 + 3] = w.w;
        }
    }
#pragma unroll
    for (int c = 0; c < C; ++c) acc[c] = 0.f;
    float m = -INFINITY, denom = 0.f;
    int beg = rowptr[node], end = rowptr[node + 1];
    int idx = beg;
    // unroll-2: both raw gathers issued before either conversion -> 2x MLP
    for (; idx + 2 <= end; idx += 2) {
        int s0 = colsrc[idx], s1 = colsrc[idx + 1];
        const float4* p0 = (const float4*)(xl + (size_t)s0 * (H * C) + h * C);
        const float4* p1 = (const float4*)(xl + (size_t)s1 * (H * C) + h * C);
        float4 raw0[C / 8], raw1[C / 8];
#pragma unroll
        for (int i = 0; i < C / 8; ++i) raw0[i] = p0[i];
#pragma unroll
        for (int i = 0; i < C / 8; ++i) raw1[i] = p1[i];
        attn_edge<C>(raw0, xrr, attv, m, denom, acc);
        attn_edge<C>(raw1, xrr, attv, m, denom, acc);
    }
    for (; idx < end; ++idx) {
        int s = colsrc[idx];
        const float4* p = (const float4*)(xl + (size_t)s * (H * C) + h * C);
        float4 raw[C / 8];
#pragma unroll
        for (int i = 0; i < C / 8; ++i) raw[i] = p[i];
        attn_edge<C>(raw, xrr, attv, m, denom, acc);
    }
    float inv = 1.f / denom;
    float* op = out + (size_t)node * (H * C) + h * C;
#pragma unroll
    for (int c = 0; c < C; c += 4) {
        float4 v;
        v.x = acc[c + 0] * inv + (CONCAT ? bias[h * C + c + 0] : 0.f);
        v.y = acc[c + 1] * inv + (CONCAT ? bias[h * C + c + 1] : 0.f);
        v.z = acc[c + 2] * inv + (CONCAT ? bias[h * C + c + 2] : 0.f);
        v.w = acc[c + 3] * inv + (CONCAT ? bias[h * C + c + 3] : 0.f);
        *(float4*)(op + c) = v;
    }
}

// ---------------- GraphNorm ----------------

__global__ __launch_bounds__(256) void k_gnred(const float* __restrict__ h, const int* __restrict__ batch,
                                               float* __restrict__ sum, float* __restrict__ sumsq, int logC) {
    int C = 1 << logC;
    int c = threadIdx.x & (C - 1);
    int row = threadIdx.x >> logC;
    int rows = 256 >> logC;
    int base = blockIdx.x * 256;
    int curg = -1;
    float s = 0.f, ss = 0.f;
    for (int r = row; r < 256; r += rows) {
        int nd = base + r;
        if (nd >= NN) break;
        int g = batch[nd];
        if (g != curg) {
            if (curg >= 0) { atomicAdd(&sum[curg * C + c], s); atomicAdd(&sumsq[curg * C + c], ss); }
            curg = g; s = 0.f; ss = 0.f;
        }
        float x = h[(size_t)nd * C + c];
        s += x; ss += x * x;
    }
    if (curg >= 0) { atomicAdd(&sum[curg * C + c], s); atomicAdd(&sumsq[curg * C + c], ss); }
}

// var(out) = E[x^2] - (2s - s^2) mu^2  where out = x - mu*s
__global__ __launch_bounds__(256) void k_gnnorm(float* __restrict__ h, const int* __restrict__ batch,
                                                const float* __restrict__ sum, const float* __restrict__ sumsq,
                                                const int* __restrict__ cnt, const float* __restrict__ w,
                                                const float* __restrict__ b, const float* __restrict__ ms,
                                                int logC) {
    int C = 1 << logC;
    int i = blockIdx.x * 256 + threadIdx.x;
    if (i >= NN * C) return;
    int nd = i >> logC, c = i & (C - 1);
    int g = batch[nd];
    float cg = fmaxf((float)cnt[g], 1.f);
    float mu = sum[g * C + c] / cg;
    float ex2 = sumsq[g * C + c] / cg;
    float s_ = ms[c];
    float var = ex2 - (2.f * s_ - s_ * s_) * mu * mu;
    float y = (h[i] - mu * s_) * rsqrtf(var + 1e-5f) * w[c] + b[c];
    h[i] = fmaxf(y, 0.f);   // fused ReLU
}

// ---------------- layer-3 head mean + bias ----------------

__global__ __launch_bounds__(256) void k_headmean(const float* __restrict__ tmp, const float* __restrict__ b3,
                                                  float* __restrict__ out) {
    int i = blockIdx.x * 256 + threadIdx.x;
    if (i >= NN * 8) return;
    int nd = i >> 3, c = i & 7;
    const float* p = tmp + (size_t)nd * 32 + c;
    out[i] = 0.25f * (p[0] + p[8] + p[16] + p[24]) + b3[c];
}

// ---------------- pool mean + linear head ----------------

__global__ __launch_bounds__(512) void k_final(const float* __restrict__ pool, const int* __restrict__ cnt,
                                               const float* __restrict__ lw, const float* __restrict__ lb,
                                               float* __restrict__ outp) {
    __shared__ float feat[512];
    int t = threadIdx.x;
    int g = t >> 3;
    float f = pool[t] / fmaxf((float)cnt[g], 1.f);
    feat[t] = f;
    outp[256 + t] = f;          // features: d_out[256 .. 768)
    __syncthreads();
    if (t < 256) {
        int g2 = t >> 2, o = t & 3;
        float a = lb[o];
#pragma unroll
        for (int cc = 0; cc < 8; ++cc) a += feat[g2 * 8 + cc] * lw[cc * 4 + o];
        outp[t] = a;            // logits: d_out[0 .. 256)
    }
}

// ---------------- host ----------------

extern "C" void kernel_launch(void* const* d_in, const int* in_sizes, int n_in,
                              void* d_out, int out_size, void* d_ws, size_t ws_size,
                              hipStream_t stream) {
    const float* x    = (const float*)d_in[0];
    const int*   ei   = (const int*)d_in[1];
    const int*   batch= (const int*)d_in[2];
    const float *w_l1 = (const float*)d_in[3],  *w_r1 = (const float*)d_in[4];
    const float *att1 = (const float*)d_in[5],  *b1   = (const float*)d_in[6];
    const float *gn1w = (const float*)d_in[7],  *gn1b = (const float*)d_in[8],  *gn1s = (const float*)d_in[9];
    const float *w_l2 = (const float*)d_in[10], *w_r2 = (const float*)d_in[11];
    const float *att2 = (const float*)d_in[12], *b2   = (const float*)d_in[13];
    const float *gn2w = (const float*)d_in[14], *gn2b = (const float*)d_in[15], *gn2s = (const float*)d_in[16];
    const float *w_l3 = (const float*)d_in[17], *w_r3 = (const float*)d_in[18];
    const float *att3 = (const float*)d_in[19], *b3   = (const float*)d_in[20];
    const float *gn3w = (const float*)d_in[21], *gn3b = (const float*)d_in[22], *gn3s = (const float*)d_in[23];
    const float *lw   = (const float*)d_in[24], *lb   = (const float*)d_in[25];

    char* ws = (char*)d_ws;
    size_t off = 0;
    auto alloc = [&](size_t bytes) -> void* {
        void* p = ws + off;
        off += (bytes + 255) & ~(size_t)255;
        return p;
    };
    __half* Ah  = (__half*)alloc((size_t)NN * 128 * 2);  // x_l (fp16) for all layers
    float*  B   = (float*)alloc((size_t)NN * 128 * 4);   // x_r / layer-out scratch
    float*  Cb  = (float*)alloc((size_t)NN * 64 * 4);    // h2 scratch
    float*  Af  = (float*)alloc((size_t)NN * 8 * 4);     // layer-3 final node features
    int* rowptr = (int*)alloc((size_t)(NN + 1) * 4);
    int* cursor = (int*)alloc((size_t)NN * 4);
    int* colsrc = (int*)alloc((size_t)ET * 4);
    int* bpos   = (int*)alloc((size_t)(NG + 1) * 4);
    int* cnt    = (int*)alloc((size_t)NG * 4);
    int* bsum   = (int*)alloc((size_t)NB * 4);
    int* boff   = (int*)alloc((size_t)NB * 4);
    char* zbase = ws + off;                              // everything below gets one memset
    int*   deg  = (int*)alloc((size_t)NN * 4);
    float* sum1 = (float*)alloc((size_t)NG * 128 * 4);
    float* sq1  = (float*)alloc((size_t)NG * 128 * 4);
    float* sum2 = (float*)alloc((size_t)NG * 64 * 4);
    float* sq2  = (float*)alloc((size_t)NG * 64 * 4);
    float* sum3 = (float*)alloc((size_t)NG * 8 * 4);
    float* sq3  = (float*)alloc((size_t)NG * 8 * 4);
    float* pool = (float*)alloc((size_t)NG * 8 * 4);
    size_t zbytes = (size_t)((ws + off) - zbase);
    hipMemsetAsync(zbase, 0, zbytes, stream);

    int gE = (ET + 255) / 256;
    k_count<<<gE, 256, 0, stream>>>(ei, deg);
    k_bounds<<<(NN + 255) / 256, 256, 0, stream>>>(batch, bpos);
    k_cnt<<<1, 64, 0, stream>>>(bpos, cnt);
    k_blksum<<<NB, 256, 0, stream>>>(deg, bsum);
    k_scanb<<<1, 256, 0, stream>>>(bsum, boff);
    k_scanc<<<NB, 256, 0, stream>>>(deg, boff, rowptr, cursor);
    k_scatter<<<gE, 256, 0, stream>>>(ei, cursor, colsrc);

    int gR = (NN + 63) / 64;          // 782 row-blocks
    int gA = (NN * H + 255) / 256;    // attention grid
    int gN = (NN + 255) / 256;        // gn-reduce grid

    // ---- layer 1: 128 -> 4x32 concat -> 128
    k_gemm<__half><<<dim3(gR, 2), 256, 0, stream>>>(x, w_l1, Ah, 128, 128);
    k_gemm<float><<<dim3(gR, 2), 256, 0, stream>>>(x, w_r1, B, 128, 128);
    k_attn<32, true><<<gA, 256, 0, stream>>>(Ah, B, rowptr, colsrc, att1, b1, B);
    k_gnred<<<gN, 256, 0, stream>>>(B, batch, sum1, sq1, 7);
    k_gnnorm<<<(NN * 128 + 255) / 256, 256, 0, stream>>>(B, batch, sum1, sq1, cnt, gn1w, gn1b, gn1s, 7);

    // ---- layer 2: 128 -> 4x16 concat -> 64
    k_gemm<__half><<<dim3(gR, 1), 256, 0, stream>>>(B, w_l2, Ah, 128, 64);
    k_gemm<float><<<dim3(gR, 1), 256, 0, stream>>>(B, w_r2, Cb, 128, 64);
    k_attn<16, true><<<gA, 256, 0, stream>>>(Ah, Cb, rowptr, colsrc, att2, b2, Cb);
    k_gnred<<<gN, 256, 0, stream>>>(Cb, batch, sum2, sq2, 6);
    k_gnnorm<<<(NN * 64 + 255) / 256, 256, 0, stream>>>(Cb, batch, sum2, sq2, cnt, gn2w, gn2b, gn2s, 6);

    // ---- layer 3: 64 -> 4x8 mean -> 8
    k_gemm<__half><<<dim3(gR, 1), 256, 0, stream>>>(Cb, w_l3, Ah, 64, 32);
    k_gemm<float><<<dim3(gR, 1), 256, 0, stream>>>(Cb, w_r3, B, 64, 32);
    k_attn<8, false><<<gA, 256, 0, stream>>>(Ah, B, rowptr, colsrc, att3, nullptr, B);
    k_headmean<<<(NN * 8 + 255) / 256, 256, 0, stream>>>(B, b3, Af);
    k_gnred<<<gN, 256, 0, stream>>>(Af, batch, sum3, sq3, 3);
    k_gnnorm<<<(NN * 8 + 255) / 256, 256, 0, stream>>>(Af, batch, sum3, sq3, cnt, gn3w, gn3b, gn3s, 3);

    // ---- global mean pool + linear
    k_gnred<<<gN, 256, 0, stream>>>(Af, batch, pool, sq3, 3);  // sq3 as throwaway sumsq
    k_final<<<1, 512, 0, stream>>>(pool, cnt, lw, lb, (float*)d_out);
}

// Round 4
// 714.118 us; speedup vs baseline: 1.5430x; 1.0076x over previous
//
#include <hip/hip_runtime.h>
#include <hip/hip_fp16.h>
#include <math.h>

#define NN 50000
#define NE 800000
#define ET (NE + NN)
#define NG 64
#define H 4
#define NB ((NN + 255) / 256)   // 196 blocks of 256 nodes

// ---------------- CSR build ----------------

__global__ __launch_bounds__(256) void k_count(const int* __restrict__ ei, int* __restrict__ deg) {
    int e = blockIdx.x * 256 + threadIdx.x;
    if (e >= ET) return;
    int d = (e < NE) ? ei[NE + e] : (e - NE);
    atomicAdd(&deg[d], 1);
}

// batch is sorted: graph boundaries without atomics.
__global__ __launch_bounds__(256) void k_bounds(const int* __restrict__ batch, int* __restrict__ bpos) {
    int i = blockIdx.x * 256 + threadIdx.x;
    if (i >= NN) return;
    int cur = batch[i];
    int prev = (i == 0) ? -1 : batch[i - 1];
    for (int g = prev + 1; g <= cur; ++g) bpos[g] = i;
    if (i == NN - 1)
        for (int g = cur + 1; g <= NG; ++g) bpos[g] = NN;
}

__global__ __launch_bounds__(64) void k_cnt(const int* __restrict__ bpos, int* __restrict__ cnt) {
    int g = threadIdx.x;
    if (g < NG) cnt[g] = bpos[g + 1] - bpos[g];
}

// ---- decoupled 3-pass exclusive scan of deg[] -> rowptr/cursor

__global__ __launch_bounds__(256) void k_blksum(const int* __restrict__ deg, int* __restrict__ bsum) {
    int i = blockIdx.x * 256 + threadIdx.x;
    int v = (i < NN) ? deg[i] : 0;
    for (int off = 32; off; off >>= 1) v += __shfl_down(v, off, 64);
    __shared__ int lds[4];
    int lane = threadIdx.x & 63, wid = threadIdx.x >> 6;
    if (lane == 0) lds[wid] = v;
    __syncthreads();
    if (threadIdx.x == 0) bsum[blockIdx.x] = lds[0] + lds[1] + lds[2] + lds[3];
}

__global__ __launch_bounds__(256) void k_scanb(const int* __restrict__ bsum, int* __restrict__ boff) {
    __shared__ int lds[256];
    int t = threadIdx.x;
    int v = (t < NB) ? bsum[t] : 0;
    lds[t] = v;
    __syncthreads();
    for (int off = 1; off < 256; off <<= 1) {
        int y = (t >= off) ? lds[t - off] : 0;
        __syncthreads();
        lds[t] += y;
        __syncthreads();
    }
    if (t < NB) boff[t] = lds[t] - v;   // exclusive
}

__global__ __launch_bounds__(256) void k_scanc(const int* __restrict__ deg, const int* __restrict__ boff,
                                               int* __restrict__ rowptr, int* __restrict__ cursor) {
    int b = blockIdx.x, t = threadIdx.x;
    int i = b * 256 + t;
    int v = (i < NN) ? deg[i] : 0;
    int lane = t & 63, wid = t >> 6;
    int x = v;
    for (int off = 1; off < 64; off <<= 1) {
        int y = __shfl_up(x, off, 64);
        if (lane >= off) x += y;
    }
    __shared__ int wsum[4];
    if (lane == 63) wsum[wid] = x;
    __syncthreads();
    int base = boff[b];
    for (int w = 0; w < wid; ++w) base += wsum[w];
    int p = base + x - v;   // exclusive prefix for node i
    if (i < NN) { rowptr[i] = p; cursor[i] = p; }
    if (i == NN - 1) rowptr[NN] = p + v;
}

__global__ __launch_bounds__(256) void k_scatter(const int* __restrict__ ei, int* __restrict__ cursor,
                                                 int* __restrict__ colsrc) {
    int e = blockIdx.x * 256 + threadIdx.x;
    if (e >= ET) return;
    int s, d;
    if (e < NE) { s = ei[e]; d = ei[NE + e]; } else { s = e - NE; d = s; }
    int pos = atomicAdd(&cursor[d], 1);
    colsrc[pos] = s;
}

// ---------------- fp32 tiled GEMM: O[NN,M] = A[NN,K] @ W[K,M] ----------------
// OT=float (x_r path) or __half (x_l path, halves attention gather bytes)

template <typename OT>
__global__ __launch_bounds__(256) void k_gemm(const float* __restrict__ A, const float* __restrict__ W,
                                              OT* __restrict__ O, int K, int M) {
    __shared__ float As[64][65];
    __shared__ float Ws[64][65];
    int row0 = blockIdx.x * 64, col0 = blockIdx.y * 64;
    int tid = threadIdx.x;
    int tx = tid & 15, ty = tid >> 4;
    float acc[4][4] = {{0.f}};
    for (int k0 = 0; k0 < K; k0 += 64) {
        for (int i = tid; i < 4096; i += 256) {
            int r = i >> 6, kk = i & 63;
            int gr = row0 + r;
            As[r][kk] = (gr < NN) ? A[(size_t)gr * K + k0 + kk] : 0.f;
        }
        for (int i = tid; i < 4096; i += 256) {
            int kk = i >> 6, cc = i & 63;
            int gc = col0 + cc;
            Ws[kk][cc] = (gc < M) ? W[(size_t)(k0 + kk) * M + gc] : 0.f;
        }
        __syncthreads();
#pragma unroll 8
        for (int kk = 0; kk < 64; ++kk) {
            float a[4], b[4];
#pragma unroll
            for (int i = 0; i < 4; ++i) a[i] = As[ty * 4 + i][kk];
#pragma unroll
            for (int j = 0; j < 4; ++j) b[j] = Ws[kk][tx * 4 + j];
#pragma unroll
            for (int i = 0; i < 4; ++i)
#pragma unroll
                for (int j = 0; j < 4; ++j) acc[i][j] += a[i] * b[j];
        }
        __syncthreads();
    }
    int c0 = col0 + tx * 4;
    if (c0 >= M) return;
#pragma unroll
    for (int i = 0; i < 4; ++i) {
        int r = row0 + ty * 4 + i;
        if (r >= NN) continue;
        if constexpr (__is_same(OT, __half)) {
            __half2 st[2];
            st[0] = __floats2half2_rn(acc[i][0], acc[i][1]);
            st[1] = __floats2half2_rn(acc[i][2], acc[i][3]);
            *(float2*)(O + (size_t)r * M + c0) = *(float2*)st;
        } else {
            float4 v = make_float4(acc[i][0], acc[i][1], acc[i][2], acc[i][3]);
            *(float4*)(O + (size_t)r * M + c0) = v;
        }
    }
}

// ---------------- GATv2 attention: EP lanes per (node, head), edge-parallel online softmax ----------------
// xl fp16 gathers; xr/out fp32; out may alias xr. EP lanes split the edge list, shuffle-merge at end.

template <int C, int EP, bool CONCAT>
__global__ __launch_bounds__(256, 3) void k_attn(const __half* __restrict__ xl, const float* __restrict__ xr,
                                                 const int* __restrict__ rowptr, const int* __restrict__ colsrc,
                                                 const float* __restrict__ att, const float* __restrict__ bias,
                                                 float* __restrict__ out) {
    int t = blockIdx.x * 256 + threadIdx.x;
    if (t >= NN * H * EP) return;
    int part = t & (EP - 1);
    int nh = t / EP;
    int node = nh >> 2, h = nh & 3;          // H = 4
    float xrr[C], attv[C], acc[C];
    {
        const float4* p = (const float4*)(xr + (size_t)node * (H * C) + h * C);
        const float4* q = (const float4*)(att + h * C);
#pragma unroll
        for (int c4 = 0; c4 < C / 4; ++c4) {
            float4 v = p[c4];
            xrr[4 * c4 + 0] = v.x; xrr[4 * c4 + 1] = v.y; xrr[4 * c4 + 2] = v.z; xrr[4 * c4 + 3] = v.w;
            float4 w = q[c4];
            attv[4 * c4 + 0] = w.x; attv[4 * c4 + 1] = w.y; attv[4 * c4 + 2] = w.z; attv[4 * c4 + 3] = w.w;
        }
    }
#pragma unroll
    for (int c = 0; c < C; ++c) acc[c] = 0.f;
    float m = -1e30f, denom = 0.f;           // finite init: empty-lane merges stay NaN-free
    int beg = rowptr[node], end = rowptr[node + 1];
    for (int idx = beg + part; idx < end; idx += EP) {
        int s = colsrc[idx];
        const float4* p = (const float4*)(xl + (size_t)s * (H * C) + h * C);
        float4 raw[C / 8];
#pragma unroll
        for (int i = 0; i < C / 8; ++i) raw[i] = p[i];
        float xv[C];
#pragma unroll
        for (int i = 0; i < C / 8; ++i) {
            const __half2* hp = (const __half2*)&raw[i];
#pragma unroll
            for (int j = 0; j < 4; ++j) {
                float2 f = __half22float2(hp[j]);
                xv[8 * i + 2 * j] = f.x;
                xv[8 * i + 2 * j + 1] = f.y;
            }
        }
        float score = 0.f;
#pragma unroll
        for (int c = 0; c < C; ++c) {
            float z = xv[c] + xrr[c];
            z = (z > 0.f) ? z : 0.2f * z;    // leaky_relu slope 0.2
            score += attv[c] * z;
        }
        float mn = fmaxf(m, score);
        float es = __expf(m - mn);
        float w = __expf(score - mn);
        denom = denom * es + w;
#pragma unroll
        for (int c = 0; c < C; ++c) acc[c] = acc[c] * es + w * xv[c];
        m = mn;
    }
    // merge the EP partial online-softmax states (butterfly over adjacent lanes)
#pragma unroll
    for (int mask = 1; mask < EP; mask <<= 1) {
        float m2 = __shfl_xor(m, mask, 64);
        float d2 = __shfl_xor(denom, mask, 64);
        float mn = fmaxf(m, m2);
        float e1 = __expf(m - mn);
        float e2 = __expf(m2 - mn);
        denom = denom * e1 + d2 * e2;
#pragma unroll
        for (int c = 0; c < C; ++c) {
            float a2 = __shfl_xor(acc[c], mask, 64);
            acc[c] = acc[c] * e1 + a2 * e2;
        }
        m = mn;
    }
    float inv = 1.f / denom;
    constexpr int CP = C / EP;               // channels written per lane
    float* op = out + (size_t)node * (H * C) + h * C + part * CP;
#pragma unroll
    for (int c = 0; c < CP; ++c) {
        float v = acc[part * CP + c] * inv;
        if (CONCAT) v += bias[h * C + part * CP + c];
        op[c] = v;
    }
}

// ---------------- GraphNorm ----------------

__global__ __launch_bounds__(256) void k_gnred(const float* __restrict__ h, const int* __restrict__ batch,
                                               float* __restrict__ sum, float* __restrict__ sumsq, int logC) {
    int C = 1 << logC;
    int c = threadIdx.x & (C - 1);
    int row = threadIdx.x >> logC;
    int rows = 256 >> logC;
    int base = blockIdx.x * 256;
    int curg = -1;
    float s = 0.f, ss = 0.f;
    for (int r = row; r < 256; r += rows) {
        int nd = base + r;
        if (nd >= NN) break;
        int g = batch[nd];
        if (g != curg) {
            if (curg >= 0) { atomicAdd(&sum[curg * C + c], s); atomicAdd(&sumsq[curg * C + c], ss); }
            curg = g; s = 0.f; ss = 0.f;
        }
        float x = h[(size_t)nd * C + c];
        s += x; ss += x * x;
    }
    if (curg >= 0) { atomicAdd(&sum[curg * C + c], s); atomicAdd(&sumsq[curg * C + c], ss); }
}

// var(out) = E[x^2] - (2s - s^2) mu^2  where out = x - mu*s
__global__ __launch_bounds__(256) void k_gnnorm(float* __restrict__ h, const int* __restrict__ batch,
                                                const float* __restrict__ sum, const float* __restrict__ sumsq,
                                                const int* __restrict__ cnt, const float* __restrict__ w,
                                                const float* __restrict__ b, const float* __restrict__ ms,
                                                int logC) {
    int C = 1 << logC;
    int i = blockIdx.x * 256 + threadIdx.x;
    if (i >= NN * C) return;
    int nd = i >> logC, c = i & (C - 1);
    int g = batch[nd];
    float cg = fmaxf((float)cnt[g], 1.f);
    float mu = sum[g * C + c] / cg;
    float ex2 = sumsq[g * C + c] / cg;
    float s_ = ms[c];
    float var = ex2 - (2.f * s_ - s_ * s_) * mu * mu;
    float y = (h[i] - mu * s_) * rsqrtf(var + 1e-5f) * w[c] + b[c];
    h[i] = fmaxf(y, 0.f);   // fused ReLU
}

// ---------------- layer-3 head mean + bias ----------------

__global__ __launch_bounds__(256) void k_headmean(const float* __restrict__ tmp, const float* __restrict__ b3,
                                                  float* __restrict__ out) {
    int i = blockIdx.x * 256 + threadIdx.x;
    if (i >= NN * 8) return;
    int nd = i >> 3, c = i & 7;
    const float* p = tmp + (size_t)nd * 32 + c;
    out[i] = 0.25f * (p[0] + p[8] + p[16] + p[24]) + b3[c];
}

// ---------------- pool mean + linear head ----------------

__global__ __launch_bounds__(512) void k_final(const float* __restrict__ pool, const int* __restrict__ cnt,
                                               const float* __restrict__ lw, const float* __restrict__ lb,
                                               float* __restrict__ outp) {
    __shared__ float feat[512];
    int t = threadIdx.x;
    int g = t >> 3;
    float f = pool[t] / fmaxf((float)cnt[g], 1.f);
    feat[t] = f;
    outp[256 + t] = f;          // features: d_out[256 .. 768)
    __syncthreads();
    if (t < 256) {
        int g2 = t >> 2, o = t & 3;
        float a = lb[o];
#pragma unroll
        for (int cc = 0; cc < 8; ++cc) a += feat[g2 * 8 + cc] * lw[cc * 4 + o];
        outp[t] = a;            // logits: d_out[0 .. 256)
    }
}

// ---------------- host ----------------

extern "C" void kernel_launch(void* const* d_in, const int* in_sizes, int n_in,
                              void* d_out, int out_size, void* d_ws, size_t ws_size,
                              hipStream_t stream) {
    const float* x    = (const float*)d_in[0];
    const int*   ei   = (const int*)d_in[1];
    const int*   batch= (const int*)d_in[2];
    const float *w_l1 = (const float*)d_in[3],  *w_r1 = (const float*)d_in[4];
    const float *att1 = (const float*)d_in[5],  *b1   = (const float*)d_in[6];
    const float *gn1w = (const float*)d_in[7],  *gn1b = (const float*)d_in[8],  *gn1s = (const float*)d_in[9];
    const float *w_l2 = (const float*)d_in[10], *w_r2 = (const float*)d_in[11];
    const float *att2 = (const float*)d_in[12], *b2   = (const float*)d_in[13];
    const float *gn2w = (const float*)d_in[14], *gn2b = (const float*)d_in[15], *gn2s = (const float*)d_in[16];
    const float *w_l3 = (const float*)d_in[17], *w_r3 = (const float*)d_in[18];
    const float *att3 = (const float*)d_in[19], *b3   = (const float*)d_in[20];
    const float *gn3w = (const float*)d_in[21], *gn3b = (const float*)d_in[22], *gn3s = (const float*)d_in[23];
    const float *lw   = (const float*)d_in[24], *lb   = (const float*)d_in[25];

    char* ws = (char*)d_ws;
    size_t off = 0;
    auto alloc = [&](size_t bytes) -> void* {
        void* p = ws + off;
        off += (bytes + 255) & ~(size_t)255;
        return p;
    };
    __half* Ah  = (__half*)alloc((size_t)NN * 128 * 2);  // x_l (fp16) for all layers
    float*  B   = (float*)alloc((size_t)NN * 128 * 4);   // x_r / layer-out scratch
    float*  Cb  = (float*)alloc((size_t)NN * 64 * 4);    // h2 scratch
    float*  Af  = (float*)alloc((size_t)NN * 8 * 4);     // layer-3 final node features
    int* rowptr = (int*)alloc((size_t)(NN + 1) * 4);
    int* cursor = (int*)alloc((size_t)NN * 4);
    int* colsrc = (int*)alloc((size_t)ET * 4);
    int* bpos   = (int*)alloc((size_t)(NG + 1) * 4);
    int* cnt    = (int*)alloc((size_t)NG * 4);
    int* bsum   = (int*)alloc((size_t)NB * 4);
    int* boff   = (int*)alloc((size_t)NB * 4);
    char* zbase = ws + off;                              // everything below gets one memset
    int*   deg  = (int*)alloc((size_t)NN * 4);
    float* sum1 = (float*)alloc((size_t)NG * 128 * 4);
    float* sq1  = (float*)alloc((size_t)NG * 128 * 4);
    float* sum2 = (float*)alloc((size_t)NG * 64 * 4);
    float* sq2  = (float*)alloc((size_t)NG * 64 * 4);
    float* sum3 = (float*)alloc((size_t)NG * 8 * 4);
    float* sq3  = (float*)alloc((size_t)NG * 8 * 4);
    float* pool = (float*)alloc((size_t)NG * 8 * 4);
    size_t zbytes = (size_t)((ws + off) - zbase);
    hipMemsetAsync(zbase, 0, zbytes, stream);

    int gE = (ET + 255) / 256;
    k_count<<<gE, 256, 0, stream>>>(ei, deg);
    k_bounds<<<(NN + 255) / 256, 256, 0, stream>>>(batch, bpos);
    k_cnt<<<1, 64, 0, stream>>>(bpos, cnt);
    k_blksum<<<NB, 256, 0, stream>>>(deg, bsum);
    k_scanb<<<1, 256, 0, stream>>>(bsum, boff);
    k_scanc<<<NB, 256, 0, stream>>>(deg, boff, rowptr, cursor);
    k_scatter<<<gE, 256, 0, stream>>>(ei, cursor, colsrc);

    int gR = (NN + 63) / 64;                 // 782 row-blocks
    int gA4 = (NN * H * 4 + 255) / 256;      // attention grid, EP=4 -> 3125 blocks
    int gN = (NN + 255) / 256;               // gn-reduce grid

    // ---- layer 1: 128 -> 4x32 concat -> 128
    k_gemm<__half><<<dim3(gR, 2), 256, 0, stream>>>(x, w_l1, Ah, 128, 128);
    k_gemm<float><<<dim3(gR, 2), 256, 0, stream>>>(x, w_r1, B, 128, 128);
    k_attn<32, 4, true><<<gA4, 256, 0, stream>>>(Ah, B, rowptr, colsrc, att1, b1, B);
    k_gnred<<<gN, 256, 0, stream>>>(B, batch, sum1, sq1, 7);
    k_gnnorm<<<(NN * 128 + 255) / 256, 256, 0, stream>>>(B, batch, sum1, sq1, cnt, gn1w, gn1b, gn1s, 7);

    // ---- layer 2: 128 -> 4x16 concat -> 64
    k_gemm<__half><<<dim3(gR, 1), 256, 0, stream>>>(B, w_l2, Ah, 128, 64);
    k_gemm<float><<<dim3(gR, 1), 256, 0, stream>>>(B, w_r2, Cb, 128, 64);
    k_attn<16, 4, true><<<gA4, 256, 0, stream>>>(Ah, Cb, rowptr, colsrc, att2, b2, Cb);
    k_gnred<<<gN, 256, 0, stream>>>(Cb, batch, sum2, sq2, 6);
    k_gnnorm<<<(NN * 64 + 255) / 256, 256, 0, stream>>>(Cb, batch, sum2, sq2, cnt, gn2w, gn2b, gn2s, 6);

    // ---- layer 3: 64 -> 4x8 mean -> 8
    k_gemm<__half><<<dim3(gR, 1), 256, 0, stream>>>(Cb, w_l3, Ah, 64, 32);
    k_gemm<float><<<dim3(gR, 1), 256, 0, stream>>>(Cb, w_r3, B, 64, 32);
    k_attn<8, 4, false><<<gA4, 256, 0, stream>>>(Ah, B, rowptr, colsrc, att3, nullptr, B);
    k_headmean<<<(NN * 8 + 255) / 256, 256, 0, stream>>>(B, b3, Af);
    k_gnred<<<gN, 256, 0, stream>>>(Af, batch, sum3, sq3, 3);
    k_gnnorm<<<(NN * 8 + 255) / 256, 256, 0, stream>>>(Af, batch, sum3, sq3, cnt, gn3w, gn3b, gn3s, 3);

    // ---- global mean pool + linear
    k_gnred<<<gN, 256, 0, stream>>>(Af, batch, pool, sq3, 3);  // sq3 as throwaway sumsq
    k_final<<<1, 512, 0, stream>>>(pool, cnt, lw, lb, (float*)d_out);
}

// Round 5
// 693.559 us; speedup vs baseline: 1.5887x; 1.0296x over previous
//
#include <hip/hip_runtime.h>
#include <hip/hip_fp16.h>
#include <math.h>

#define NN 50000
#define NE 800000
#define ET (NE + NN)
#define NG 64
#define H 4
#define NB ((NN + 255) / 256)   // 196 blocks of 256 nodes

// ---------------- CSR build ----------------

__global__ __launch_bounds__(256) void k_count(const int* __restrict__ ei, int* __restrict__ deg) {
    int e = blockIdx.x * 256 + threadIdx.x;
    if (e >= ET) return;
    int d = (e < NE) ? ei[NE + e] : (e - NE);
    atomicAdd(&deg[d], 1);
}

// batch is sorted: graph boundaries without atomics.
__global__ __launch_bounds__(256) void k_bounds(const int* __restrict__ batch, int* __restrict__ bpos) {
    int i = blockIdx.x * 256 + threadIdx.x;
    if (i >= NN) return;
    int cur = batch[i];
    int prev = (i == 0) ? -1 : batch[i - 1];
    for (int g = prev + 1; g <= cur; ++g) bpos[g] = i;
    if (i == NN - 1)
        for (int g = cur + 1; g <= NG; ++g) bpos[g] = NN;
}

__global__ __launch_bounds__(64) void k_cnt(const int* __restrict__ bpos, int* __restrict__ cnt) {
    int g = threadIdx.x;
    if (g < NG) cnt[g] = bpos[g + 1] - bpos[g];
}

// ---- decoupled 3-pass exclusive scan of deg[] -> rowptr/cursor

__global__ __launch_bounds__(256) void k_blksum(const int* __restrict__ deg, int* __restrict__ bsum) {
    int i = blockIdx.x * 256 + threadIdx.x;
    int v = (i < NN) ? deg[i] : 0;
    for (int off = 32; off; off >>= 1) v += __shfl_down(v, off, 64);
    __shared__ int lds[4];
    int lane = threadIdx.x & 63, wid = threadIdx.x >> 6;
    if (lane == 0) lds[wid] = v;
    __syncthreads();
    if (threadIdx.x == 0) bsum[blockIdx.x] = lds[0] + lds[1] + lds[2] + lds[3];
}

__global__ __launch_bounds__(256) void k_scanb(const int* __restrict__ bsum, int* __restrict__ boff) {
    __shared__ int lds[256];
    int t = threadIdx.x;
    int v = (t < NB) ? bsum[t] : 0;
    lds[t] = v;
    __syncthreads();
    for (int off = 1; off < 256; off <<= 1) {
        int y = (t >= off) ? lds[t - off] : 0;
        __syncthreads();
        lds[t] += y;
        __syncthreads();
    }
    if (t < NB) boff[t] = lds[t] - v;   // exclusive
}

__global__ __launch_bounds__(256) void k_scanc(const int* __restrict__ deg, const int* __restrict__ boff,
                                               int* __restrict__ rowptr, int* __restrict__ cursor) {
    int b = blockIdx.x, t = threadIdx.x;
    int i = b * 256 + t;
    int v = (i < NN) ? deg[i] : 0;
    int lane = t & 63, wid = t >> 6;
    int x = v;
    for (int off = 1; off < 64; off <<= 1) {
        int y = __shfl_up(x, off, 64);
        if (lane >= off) x += y;
    }
    __shared__ int wsum[4];
    if (lane == 63) wsum[wid] = x;
    __syncthreads();
    int base = boff[b];
    for (int w = 0; w < wid; ++w) base += wsum[w];
    int p = base + x - v;   // exclusive prefix for node i
    if (i < NN) { rowptr[i] = p; cursor[i] = p; }
    if (i == NN - 1) rowptr[NN] = p + v;
}

__global__ __launch_bounds__(256) void k_scatter(const int* __restrict__ ei, int* __restrict__ cursor,
                                                 int* __restrict__ colsrc) {
    int e = blockIdx.x * 256 + threadIdx.x;
    if (e >= ET) return;
    int s, d;
    if (e < NE) { s = ei[e]; d = ei[NE + e]; } else { s = e - NE; d = s; }
    int pos = atomicAdd(&cursor[d], 1);
    colsrc[pos] = s;
}

// ---------------- fp32 tiled GEMM: O[NN,M] = A[NN,K] @ W[K,M] ----------------
// OT=float (x_r path) or __half (x_l path, halves attention gather bytes)

template <typename OT>
__global__ __launch_bounds__(256) void k_gemm(const float* __restrict__ A, const float* __restrict__ W,
                                              OT* __restrict__ O, int K, int M) {
    __shared__ float As[64][65];
    __shared__ float Ws[64][65];
    int row0 = blockIdx.x * 64, col0 = blockIdx.y * 64;
    int tid = threadIdx.x;
    int tx = tid & 15, ty = tid >> 4;
    float acc[4][4] = {{0.f}};
    for (int k0 = 0; k0 < K; k0 += 64) {
        for (int i = tid; i < 4096; i += 256) {
            int r = i >> 6, kk = i & 63;
            int gr = row0 + r;
            As[r][kk] = (gr < NN) ? A[(size_t)gr * K + k0 + kk] : 0.f;
        }
        for (int i = tid; i < 4096; i += 256) {
            int kk = i >> 6, cc = i & 63;
            int gc = col0 + cc;
            Ws[kk][cc] = (gc < M) ? W[(size_t)(k0 + kk) * M + gc] : 0.f;
        }
        __syncthreads();
#pragma unroll 8
        for (int kk = 0; kk < 64; ++kk) {
            float a[4], b[4];
#pragma unroll
            for (int i = 0; i < 4; ++i) a[i] = As[ty * 4 + i][kk];
#pragma unroll
            for (int j = 0; j < 4; ++j) b[j] = Ws[kk][tx * 4 + j];
#pragma unroll
            for (int i = 0; i < 4; ++i)
#pragma unroll
                for (int j = 0; j < 4; ++j) acc[i][j] += a[i] * b[j];
        }
        __syncthreads();
    }
    int c0 = col0 + tx * 4;
    if (c0 >= M) return;
#pragma unroll
    for (int i = 0; i < 4; ++i) {
        int r = row0 + ty * 4 + i;
        if (r >= NN) continue;
        if constexpr (__is_same(OT, __half)) {
            __half2 st[2];
            st[0] = __floats2half2_rn(acc[i][0], acc[i][1]);
            st[1] = __floats2half2_rn(acc[i][2], acc[i][3]);
            *(float2*)(O + (size_t)r * M + c0) = *(float2*)st;
        } else {
            float4 v = make_float4(acc[i][0], acc[i][1], acc[i][2], acc[i][3]);
            *(float4*)(O + (size_t)r * M + c0) = v;
        }
    }
}

// ---------------- GATv2 attention: channel-split, EP lanes cooperate per (node,head) ----------------
// Lane `part` of an EP-group owns channels [part*CP, (part+1)*CP). All EP lanes walk the SAME edge
// list; per edge each lane loads its contiguous fp16 slice (coalesced 2C bytes/edge), partial-dot +
// shfl_xor reduce gives every lane the full score; each lane updates only its acc slice. No spills,
// no end-merge, no duplicate xr reads. out may alias xr.

template <int CP>
__device__ __forceinline__ void load_h16(const __half* __restrict__ p, float* __restrict__ xv) {
    if constexpr (CP == 8) {
        float4 r = *(const float4*)p;
        const __half2* hp = (const __half2*)&r;
#pragma unroll
        for (int j = 0; j < 4; ++j) {
            float2 f = __half22float2(hp[j]);
            xv[2 * j] = f.x; xv[2 * j + 1] = f.y;
        }
    } else if constexpr (CP == 4) {
        float2 r = *(const float2*)p;
        const __half2* hp = (const __half2*)&r;
#pragma unroll
        for (int j = 0; j < 2; ++j) {
            float2 f = __half22float2(hp[j]);
            xv[2 * j] = f.x; xv[2 * j + 1] = f.y;
        }
    } else {
        __half2 r = *(const __half2*)p;
        float2 f = __half22float2(r);
        xv[0] = f.x; xv[1] = f.y;
    }
}

template <int C, int EP, bool CONCAT>
__global__ __launch_bounds__(256, 4) void k_attn(const __half* __restrict__ xl, const float* __restrict__ xr,
                                                 const int* __restrict__ rowptr, const int* __restrict__ colsrc,
                                                 const float* __restrict__ att, const float* __restrict__ bias,
                                                 float* __restrict__ out) {
    constexpr int CP = C / EP;
    int t = blockIdx.x * 256 + threadIdx.x;
    int part = t & (EP - 1);
    int nh = t >> 2;                          // EP == 4
    if (nh >= NN * H) return;
    int node = nh >> 2, h = nh & 3;           // H == 4
    int cbase = h * C + part * CP;
    float xrr[CP], attv[CP], acc[CP];
    {
        const float* p = xr + (size_t)node * (H * C) + cbase;
        const float* q = att + cbase;
#pragma unroll
        for (int c = 0; c < CP; ++c) { xrr[c] = p[c]; attv[c] = q[c]; acc[c] = 0.f; }
    }
    float m = -1e30f, denom = 0.f;
    int beg = rowptr[node], end = rowptr[node + 1];

    auto process = [&](const float* __restrict__ xv) {
        float part_s = 0.f;
#pragma unroll
        for (int c = 0; c < CP; ++c) {
            float z = xv[c] + xrr[c];
            z = (z > 0.f) ? z : 0.2f * z;     // leaky_relu slope 0.2
            part_s += attv[c] * z;
        }
        float score = part_s;
#pragma unroll
        for (int mask = 1; mask < EP; mask <<= 1) score += __shfl_xor(score, mask, 64);
        float mn = fmaxf(m, score);
        float es = __expf(m - mn);
        float w = __expf(score - mn);
        denom = denom * es + w;
#pragma unroll
        for (int c = 0; c < CP; ++c) acc[c] = acc[c] * es + w * xv[c];
        m = mn;
    };

    int idx = beg;
    for (; idx + 2 <= end; idx += 2) {
        int s0 = colsrc[idx], s1 = colsrc[idx + 1];
        float xv0[CP], xv1[CP];
        load_h16<CP>(xl + (size_t)s0 * (H * C) + cbase, xv0);
        load_h16<CP>(xl + (size_t)s1 * (H * C) + cbase, xv1);
        process(xv0);
        process(xv1);
    }
    if (idx < end) {
        int s = colsrc[idx];
        float xv[CP];
        load_h16<CP>(xl + (size_t)s * (H * C) + cbase, xv);
        process(xv);
    }

    float inv = 1.f / denom;
    float* op = out + (size_t)node * (H * C) + cbase;
    float v[CP];
#pragma unroll
    for (int c = 0; c < CP; ++c) {
        v[c] = acc[c] * inv;
        if (CONCAT) v[c] += bias[cbase + c];
    }
    if constexpr (CP == 8) {
        *(float4*)(op) = make_float4(v[0], v[1], v[2], v[3]);
        *(float4*)(op + 4) = make_float4(v[4], v[5], v[6], v[7]);
    } else if constexpr (CP == 4) {
        *(float4*)(op) = make_float4(v[0], v[1], v[2], v[3]);
    } else {
        *(float2*)(op) = make_float2(v[0], v[1]);
    }
}

// ---------------- GraphNorm ----------------

__global__ __launch_bounds__(256) void k_gnred(const float* __restrict__ h, const int* __restrict__ batch,
                                               float* __restrict__ sum, float* __restrict__ sumsq, int logC) {
    int C = 1 << logC;
    int c = threadIdx.x & (C - 1);
    int row = threadIdx.x >> logC;
    int rows = 256 >> logC;
    int base = blockIdx.x * 256;
    int curg = -1;
    float s = 0.f, ss = 0.f;
    for (int r = row; r < 256; r += rows) {
        int nd = base + r;
        if (nd >= NN) break;
        int g = batch[nd];
        if (g != curg) {
            if (curg >= 0) { atomicAdd(&sum[curg * C + c], s); atomicAdd(&sumsq[curg * C + c], ss); }
            curg = g; s = 0.f; ss = 0.f;
        }
        float x = h[(size_t)nd * C + c];
        s += x; ss += x * x;
    }
    if (curg >= 0) { atomicAdd(&sum[curg * C + c], s); atomicAdd(&sumsq[curg * C + c], ss); }
}

// var(out) = E[x^2] - (2s - s^2) mu^2  where out = x - mu*s
__global__ __launch_bounds__(256) void k_gnnorm(float* __restrict__ h, const int* __restrict__ batch,
                                                const float* __restrict__ sum, const float* __restrict__ sumsq,
                                                const int* __restrict__ cnt, const float* __restrict__ w,
                                                const float* __restrict__ b, const float* __restrict__ ms,
                                                int logC) {
    int C = 1 << logC;
    int i = blockIdx.x * 256 + threadIdx.x;
    if (i >= NN * C) return;
    int nd = i >> logC, c = i & (C - 1);
    int g = batch[nd];
    float cg = fmaxf((float)cnt[g], 1.f);
    float mu = sum[g * C + c] / cg;
    float ex2 = sumsq[g * C + c] / cg;
    float s_ = ms[c];
    float var = ex2 - (2.f * s_ - s_ * s_) * mu * mu;
    float y = (h[i] - mu * s_) * rsqrtf(var + 1e-5f) * w[c] + b[c];
    h[i] = fmaxf(y, 0.f);   // fused ReLU
}

// ---------------- layer-3 head mean + bias ----------------

__global__ __launch_bounds__(256) void k_headmean(const float* __restrict__ tmp, const float* __restrict__ b3,
                                                  float* __restrict__ out) {
    int i = blockIdx.x * 256 + threadIdx.x;
    if (i >= NN * 8) return;
    int nd = i >> 3, c = i & 7;
    const float* p = tmp + (size_t)nd * 32 + c;
    out[i] = 0.25f * (p[0] + p[8] + p[16] + p[24]) + b3[c];
}

// ---------------- pool mean + linear head ----------------

__global__ __launch_bounds__(512) void k_final(const float* __restrict__ pool, const int* __restrict__ cnt,
                                               const float* __restrict__ lw, const float* __restrict__ lb,
                                               float* __restrict__ outp) {
    __shared__ float feat[512];
    int t = threadIdx.x;
    int g = t >> 3;
    float f = pool[t] / fmaxf((float)cnt[g], 1.f);
    feat[t] = f;
    outp[256 + t] = f;          // features: d_out[256 .. 768)
    __syncthreads();
    if (t < 256) {
        int g2 = t >> 2, o = t & 3;
        float a = lb[o];
#pragma unroll
        for (int cc = 0; cc < 8; ++cc) a += feat[g2 * 8 + cc] * lw[cc * 4 + o];
        outp[t] = a;            // logits: d_out[0 .. 256)
    }
}

// ---------------- host ----------------

extern "C" void kernel_launch(void* const* d_in, const int* in_sizes, int n_in,
                              void* d_out, int out_size, void* d_ws, size_t ws_size,
                              hipStream_t stream) {
    const float* x    = (const float*)d_in[0];
    const int*   ei   = (const int*)d_in[1];
    const int*   batch= (const int*)d_in[2];
    const float *w_l1 = (const float*)d_in[3],  *w_r1 = (const float*)d_in[4];
    const float *att1 = (const float*)d_in[5],  *b1   = (const float*)d_in[6];
    const float *gn1w = (const float*)d_in[7],  *gn1b = (const float*)d_in[8],  *gn1s = (const float*)d_in[9];
    const float *w_l2 = (const float*)d_in[10], *w_r2 = (const float*)d_in[11];
    const float *att2 = (const float*)d_in[12], *b2   = (const float*)d_in[13];
    const float *gn2w = (const float*)d_in[14], *gn2b = (const float*)d_in[15], *gn2s = (const float*)d_in[16];
    const float *w_l3 = (const float*)d_in[17], *w_r3 = (const float*)d_in[18];
    const float *att3 = (const float*)d_in[19], *b3   = (const float*)d_in[20];
    const float *gn3w = (const float*)d_in[21], *gn3b = (const float*)d_in[22], *gn3s = (const float*)d_in[23];
    const float *lw   = (const float*)d_in[24], *lb   = (const float*)d_in[25];

    char* ws = (char*)d_ws;
    size_t off = 0;
    auto alloc = [&](size_t bytes) -> void* {
        void* p = ws + off;
        off += (bytes + 255) & ~(size_t)255;
        return p;
    };
    __half* Ah  = (__half*)alloc((size_t)NN * 128 * 2);  // x_l (fp16) for all layers
    float*  B   = (float*)alloc((size_t)NN * 128 * 4);   // x_r / layer-out scratch
    float*  Cb  = (float*)alloc((size_t)NN * 64 * 4);    // h2 scratch
    float*  Af  = (float*)alloc((size_t)NN * 8 * 4);     // layer-3 final node features
    int* rowptr = (int*)alloc((size_t)(NN + 1) * 4);
    int* cursor = (int*)alloc((size_t)NN * 4);
    int* colsrc = (int*)alloc((size_t)ET * 4);
    int* bpos   = (int*)alloc((size_t)(NG + 1) * 4);
    int* cnt    = (int*)alloc((size_t)NG * 4);
    int* bsum   = (int*)alloc((size_t)NB * 4);
    int* boff   = (int*)alloc((size_t)NB * 4);
    char* zbase = ws + off;                              // everything below gets one memset
    int*   deg  = (int*)alloc((size_t)NN * 4);
    float* sum1 = (float*)alloc((size_t)NG * 128 * 4);
    float* sq1  = (float*)alloc((size_t)NG * 128 * 4);
    float* sum2 = (float*)alloc((size_t)NG * 64 * 4);
    float* sq2  = (float*)alloc((size_t)NG * 64 * 4);
    float* sum3 = (float*)alloc((size_t)NG * 8 * 4);
    float* sq3  = (float*)alloc((size_t)NG * 8 * 4);
    float* pool = (float*)alloc((size_t)NG * 8 * 4);
    size_t zbytes = (size_t)((ws + off) - zbase);
    hipMemsetAsync(zbase, 0, zbytes, stream);

    int gE = (ET + 255) / 256;
    k_count<<<gE, 256, 0, stream>>>(ei, deg);
    k_bounds<<<(NN + 255) / 256, 256, 0, stream>>>(batch, bpos);
    k_cnt<<<1, 64, 0, stream>>>(bpos, cnt);
    k_blksum<<<NB, 256, 0, stream>>>(deg, bsum);
    k_scanb<<<1, 256, 0, stream>>>(bsum, boff);
    k_scanc<<<NB, 256, 0, stream>>>(deg, boff, rowptr, cursor);
    k_scatter<<<gE, 256, 0, stream>>>(ei, cursor, colsrc);

    int gR = (NN + 63) / 64;                 // 782 row-blocks
    int gA4 = (NN * H * 4) / 256;            // attention grid, EP=4 -> 3125 blocks exact
    int gN = (NN + 255) / 256;               // gn-reduce grid

    // ---- layer 1: 128 -> 4x32 concat -> 128
    k_gemm<__half><<<dim3(gR, 2), 256, 0, stream>>>(x, w_l1, Ah, 128, 128);
    k_gemm<float><<<dim3(gR, 2), 256, 0, stream>>>(x, w_r1, B, 128, 128);
    k_attn<32, 4, true><<<gA4, 256, 0, stream>>>(Ah, B, rowptr, colsrc, att1, b1, B);
    k_gnred<<<gN, 256, 0, stream>>>(B, batch, sum1, sq1, 7);
    k_gnnorm<<<(NN * 128 + 255) / 256, 256, 0, stream>>>(B, batch, sum1, sq1, cnt, gn1w, gn1b, gn1s, 7);

    // ---- layer 2: 128 -> 4x16 concat -> 64
    k_gemm<__half><<<dim3(gR, 1), 256, 0, stream>>>(B, w_l2, Ah, 128, 64);
    k_gemm<float><<<dim3(gR, 1), 256, 0, stream>>>(B, w_r2, Cb, 128, 64);
    k_attn<16, 4, true><<<gA4, 256, 0, stream>>>(Ah, Cb, rowptr, colsrc, att2, b2, Cb);
    k_gnred<<<gN, 256, 0, stream>>>(Cb, batch, sum2, sq2, 6);
    k_gnnorm<<<(NN * 64 + 255) / 256, 256, 0, stream>>>(Cb, batch, sum2, sq2, cnt, gn2w, gn2b, gn2s, 6);

    // ---- layer 3: 64 -> 4x8 mean -> 8
    k_gemm<__half><<<dim3(gR, 1), 256, 0, stream>>>(Cb, w_l3, Ah, 64, 32);
    k_gemm<float><<<dim3(gR, 1), 256, 0, stream>>>(Cb, w_r3, B, 64, 32);
    k_attn<8, 4, false><<<gA4, 256, 0, stream>>>(Ah, B, rowptr, colsrc, att3, nullptr, B);
    k_headmean<<<(NN * 8 + 255) / 256, 256, 0, stream>>>(B, b3, Af);
    k_gnred<<<gN, 256, 0, stream>>>(Af, batch, sum3, sq3, 3);
    k_gnnorm<<<(NN * 8 + 255) / 256, 256, 0, stream>>>(Af, batch, sum3, sq3, cnt, gn3w, gn3b, gn3s, 3);

    // ---- global mean pool + linear
    k_gnred<<<gN, 256, 0, stream>>>(Af, batch, pool, sq3, 3);  // sq3 as throwaway sumsq
    k_final<<<1, 512, 0, stream>>>(pool, cnt, lw, lb, (float*)d_out);
}

// Round 6
// 545.793 us; speedup vs baseline: 2.0188x; 1.2707x over previous
//
#include <hip/hip_runtime.h>
#include <hip/hip_fp16.h>
#include <math.h>

#define NN 50000
#define NE 800000
#define ET (NE + NN)
#define NG 64
#define H 4
#define NB ((NN + 255) / 256)   // 196 blocks of 256 nodes

typedef _Float16 half8 __attribute__((ext_vector_type(8)));
typedef float floatx4 __attribute__((ext_vector_type(4)));

// ---------------- CSR build ----------------

__global__ __launch_bounds__(256) void k_count(const int* __restrict__ ei, int* __restrict__ deg) {
    int e = blockIdx.x * 256 + threadIdx.x;
    if (e >= ET) return;
    int d = (e < NE) ? ei[NE + e] : (e - NE);
    atomicAdd(&deg[d], 1);
}

// batch is sorted: graph boundaries without atomics.
__global__ __launch_bounds__(256) void k_bounds(const int* __restrict__ batch, int* __restrict__ bpos) {
    int i = blockIdx.x * 256 + threadIdx.x;
    if (i >= NN) return;
    int cur = batch[i];
    int prev = (i == 0) ? -1 : batch[i - 1];
    for (int g = prev + 1; g <= cur; ++g) bpos[g] = i;
    if (i == NN - 1)
        for (int g = cur + 1; g <= NG; ++g) bpos[g] = NN;
}

__global__ __launch_bounds__(64) void k_cnt(const int* __restrict__ bpos, int* __restrict__ cnt) {
    int g = threadIdx.x;
    if (g < NG) cnt[g] = bpos[g + 1] - bpos[g];
}

// ---- decoupled 3-pass exclusive scan of deg[] -> rowptr/cursor

__global__ __launch_bounds__(256) void k_blksum(const int* __restrict__ deg, int* __restrict__ bsum) {
    int i = blockIdx.x * 256 + threadIdx.x;
    int v = (i < NN) ? deg[i] : 0;
    for (int off = 32; off; off >>= 1) v += __shfl_down(v, off, 64);
    __shared__ int lds[4];
    int lane = threadIdx.x & 63, wid = threadIdx.x >> 6;
    if (lane == 0) lds[wid] = v;
    __syncthreads();
    if (threadIdx.x == 0) bsum[blockIdx.x] = lds[0] + lds[1] + lds[2] + lds[3];
}

__global__ __launch_bounds__(256) void k_scanb(const int* __restrict__ bsum, int* __restrict__ boff) {
    __shared__ int lds[256];
    int t = threadIdx.x;
    int v = (t < NB) ? bsum[t] : 0;
    lds[t] = v;
    __syncthreads();
    for (int off = 1; off < 256; off <<= 1) {
        int y = (t >= off) ? lds[t - off] : 0;
        __syncthreads();
        lds[t] += y;
        __syncthreads();
    }
    if (t < NB) boff[t] = lds[t] - v;   // exclusive
}

__global__ __launch_bounds__(256) void k_scanc(const int* __restrict__ deg, const int* __restrict__ boff,
                                               int* __restrict__ rowptr, int* __restrict__ cursor) {
    int b = blockIdx.x, t = threadIdx.x;
    int i = b * 256 + t;
    int v = (i < NN) ? deg[i] : 0;
    int lane = t & 63, wid = t >> 6;
    int x = v;
    for (int off = 1; off < 64; off <<= 1) {
        int y = __shfl_up(x, off, 64);
        if (lane >= off) x += y;
    }
    __shared__ int wsum[4];
    if (lane == 63) wsum[wid] = x;
    __syncthreads();
    int base = boff[b];
    for (int w = 0; w < wid; ++w) base += wsum[w];
    int p = base + x - v;   // exclusive prefix for node i
    if (i < NN) { rowptr[i] = p; cursor[i] = p; }
    if (i == NN - 1) rowptr[NN] = p + v;
}

__global__ __launch_bounds__(256) void k_scatter(const int* __restrict__ ei, int* __restrict__ cursor,
                                                 int* __restrict__ colsrc) {
    int e = blockIdx.x * 256 + threadIdx.x;
    if (e >= ET) return;
    int s, d;
    if (e < NE) { s = ei[e]; d = ei[NE + e]; } else { s = e - NE; d = s; }
    int pos = atomicAdd(&cursor[d], 1);
    colsrc[pos] = s;
}

// ---------------- fp32 -> fp16 cast (layer-1 GEMM input) ----------------

__global__ __launch_bounds__(256) void k_cast(const float* __restrict__ x, __half* __restrict__ xh) {
    int i = blockIdx.x * 256 + threadIdx.x;       // one thread = 8 elements; NN*128 % 8 == 0
    size_t base = (size_t)i * 8;
    if (base >= (size_t)NN * 128) return;
    const float4* p = (const float4*)(x + base);
    float4 a = p[0], b = p[1];
    half8 h;
    h[0] = (_Float16)a.x; h[1] = (_Float16)a.y; h[2] = (_Float16)a.z; h[3] = (_Float16)a.w;
    h[4] = (_Float16)b.x; h[5] = (_Float16)b.y; h[6] = (_Float16)b.z; h[7] = (_Float16)b.w;
    *(half8*)(xh + base) = h;
}

// ---------------- fused dual MFMA GEMM ----------------
// O_l[NN,M2] (fp16) = A @ Wl ; O_r[NN,M2] (fp32) = A @ Wr.  A fp16 [NN,K] row-major.
// Wl|Wr cast+transposed to LDS Wt[n][k] fp16 with XOR chunk-swizzle (no pad; l1 = exactly 64KB).
// 4 waves: CG col-groups x (4/CG) row-groups of 16 rows. mfma_f32_16x16x32_f16.
// Verified layouts: A[m=lane&15][k=quad*8+j]; B=Wt[n=lane&15][k=quad*8+j]; D col=lane&15,row=quad*4+reg.

template <int K, int M2, int CG>
__global__ __launch_bounds__(256) void k_dualgemm(const __half* __restrict__ Ain,
                                                  const float* __restrict__ Wl, const float* __restrict__ Wr,
                                                  __half* __restrict__ Ol, float* __restrict__ Or) {
    constexpr int MTOT = 2 * M2;
    constexpr int WCOLS = MTOT / CG;      // cols per wave
    constexpr int NT = WCOLS / 16;        // 16-col MFMA tiles per wave
    constexpr int RPB = (4 / CG) * 16;    // rows per block
    constexpr int KC = K / 8;             // 16B chunks per Wt row
    __shared__ _Float16 Wt[MTOT * K];

    int tid = threadIdx.x;
    // stage W: global reads coalesced over n; swizzled LDS writes
    for (int idx = tid; idx < MTOT * K; idx += 256) {
        int n = idx & (MTOT - 1);
        int k = idx / MTOT;
        float w = (n < M2) ? Wl[k * M2 + n] : Wr[k * M2 + (n - M2)];
        int c8 = k >> 3, o = k & 7;
        int pc = (c8 + n) & (KC - 1);
        Wt[n * K + pc * 8 + o] = (_Float16)w;
    }
    __syncthreads();

    int wid = tid >> 6, lane = tid & 63;
    int q = lane >> 4, l15 = lane & 15;
    int colg = wid & (CG - 1);
    int rowg = wid / CG;
    int r0 = blockIdx.x * RPB + rowg * 16;
    int n0 = colg * WCOLS;
    int arow = min(r0 + l15, NN - 1);
    const _Float16* A = (const _Float16*)Ain;
    const _Float16* ap = A + (size_t)arow * K + q * 8;

    floatx4 acc[NT];
#pragma unroll
    for (int t = 0; t < NT; ++t) acc[t] = (floatx4){0.f, 0.f, 0.f, 0.f};

#pragma unroll
    for (int kt = 0; kt < K / 32; ++kt) {
        int k0 = kt * 32;
        half8 a8 = *(const half8*)(ap + k0);
        int c8l = (k0 >> 3) + q;
#pragma unroll
        for (int t = 0; t < NT; ++t) {
            int n = n0 + t * 16 + l15;
            int pc = (c8l + n) & (KC - 1);
            half8 b8 = *(const half8*)(&Wt[n * K + pc * 8]);
            acc[t] = __builtin_amdgcn_mfma_f32_16x16x32_f16(a8, b8, acc[t], 0, 0, 0);
        }
    }

#pragma unroll
    for (int t = 0; t < NT; ++t) {
        int cn = n0 + t * 16 + l15;
#pragma unroll
        for (int reg = 0; reg < 4; ++reg) {
            int r = r0 + q * 4 + reg;
            if (r < NN) {
                if (cn < M2) Ol[(size_t)r * M2 + cn] = __float2half(acc[t][reg]);
                else         Or[(size_t)r * M2 + (cn - M2)] = acc[t][reg];
            }
        }
    }
}

// ---------------- GATv2 attention: channel-split, EP lanes cooperate per (node,head) ----------------

template <int CP>
__device__ __forceinline__ void load_h16(const __half* __restrict__ p, float* __restrict__ xv) {
    if constexpr (CP == 8) {
        float4 r = *(const float4*)p;
        const __half2* hp = (const __half2*)&r;
#pragma unroll
        for (int j = 0; j < 4; ++j) {
            float2 f = __half22float2(hp[j]);
            xv[2 * j] = f.x; xv[2 * j + 1] = f.y;
        }
    } else if constexpr (CP == 4) {
        float2 r = *(const float2*)p;
        const __half2* hp = (const __half2*)&r;
#pragma unroll
        for (int j = 0; j < 2; ++j) {
            float2 f = __half22float2(hp[j]);
            xv[2 * j] = f.x; xv[2 * j + 1] = f.y;
        }
    } else {
        __half2 r = *(const __half2*)p;
        float2 f = __half22float2(r);
        xv[0] = f.x; xv[1] = f.y;
    }
}

template <int C, int EP, bool CONCAT>
__global__ __launch_bounds__(256, 4) void k_attn(const __half* __restrict__ xl, const float* __restrict__ xr,
                                                 const int* __restrict__ rowptr, const int* __restrict__ colsrc,
                                                 const float* __restrict__ att, const float* __restrict__ bias,
                                                 float* __restrict__ out) {
    constexpr int CP = C / EP;
    int t = blockIdx.x * 256 + threadIdx.x;
    int part = t & (EP - 1);
    int nh = t >> 2;                          // EP == 4
    if (nh >= NN * H) return;
    int node = nh >> 2, h = nh & 3;           // H == 4
    int cbase = h * C + part * CP;
    float xrr[CP], attv[CP], acc[CP];
    {
        const float* p = xr + (size_t)node * (H * C) + cbase;
        const float* q = att + cbase;
#pragma unroll
        for (int c = 0; c < CP; ++c) { xrr[c] = p[c]; attv[c] = q[c]; acc[c] = 0.f; }
    }
    float m = -1e30f, denom = 0.f;
    int beg = rowptr[node], end = rowptr[node + 1];

    auto process = [&](const float* __restrict__ xv) {
        float part_s = 0.f;
#pragma unroll
        for (int c = 0; c < CP; ++c) {
            float z = xv[c] + xrr[c];
            z = (z > 0.f) ? z : 0.2f * z;     // leaky_relu slope 0.2
            part_s += attv[c] * z;
        }
        float score = part_s;
#pragma unroll
        for (int mask = 1; mask < EP; mask <<= 1) score += __shfl_xor(score, mask, 64);
        float mn = fmaxf(m, score);
        float es = __expf(m - mn);
        float w = __expf(score - mn);
        denom = denom * es + w;
#pragma unroll
        for (int c = 0; c < CP; ++c) acc[c] = acc[c] * es + w * xv[c];
        m = mn;
    };

    int idx = beg;
    for (; idx + 2 <= end; idx += 2) {
        int s0 = colsrc[idx], s1 = colsrc[idx + 1];
        float xv0[CP], xv1[CP];
        load_h16<CP>(xl + (size_t)s0 * (H * C) + cbase, xv0);
        load_h16<CP>(xl + (size_t)s1 * (H * C) + cbase, xv1);
        process(xv0);
        process(xv1);
    }
    if (idx < end) {
        int s = colsrc[idx];
        float xv[CP];
        load_h16<CP>(xl + (size_t)s * (H * C) + cbase, xv);
        process(xv);
    }

    float inv = 1.f / denom;
    float* op = out + (size_t)node * (H * C) + cbase;
    float v[CP];
#pragma unroll
    for (int c = 0; c < CP; ++c) {
        v[c] = acc[c] * inv;
        if (CONCAT) v[c] += bias[cbase + c];
    }
    if constexpr (CP == 8) {
        *(float4*)(op) = make_float4(v[0], v[1], v[2], v[3]);
        *(float4*)(op + 4) = make_float4(v[4], v[5], v[6], v[7]);
    } else if constexpr (CP == 4) {
        *(float4*)(op) = make_float4(v[0], v[1], v[2], v[3]);
    } else {
        *(float2*)(op) = make_float2(v[0], v[1]);
    }
}

// ---------------- GraphNorm ----------------
// 64 nodes/block, compile-time trip counts -> unrolled, loads batched; run-length flush.

template <int LOGC>
__global__ __launch_bounds__(256) void k_gnred(const float* __restrict__ h, const int* __restrict__ batch,
                                               float* __restrict__ sum, float* __restrict__ sumsq) {
    constexpr int C = 1 << LOGC;
    constexpr int ROWS = 256 >> LOGC;
    constexpr int NPB = 64;
    int c = threadIdx.x & (C - 1);
    int row = threadIdx.x >> LOGC;
    int base = blockIdx.x * NPB;
    int curg = -1;
    float s = 0.f, ss = 0.f;
#pragma unroll
    for (int r = row; r < NPB; r += ROWS) {
        int nd = base + r;
        if (nd >= NN) break;
        int g = batch[nd];
        if (g != curg) {
            if (curg >= 0) { atomicAdd(&sum[curg * C + c], s); atomicAdd(&sumsq[curg * C + c], ss); }
            curg = g; s = 0.f; ss = 0.f;
        }
        float x = h[(size_t)nd * C + c];
        s += x; ss += x * x;
    }
    if (curg >= 0) { atomicAdd(&sum[curg * C + c], s); atomicAdd(&sumsq[curg * C + c], ss); }
}

// var(out) = E[x^2] - (2s - s^2) mu^2  where out = x - mu*s; optional fp16 copy for next GEMM
__global__ __launch_bounds__(256) void k_gnnorm(float* __restrict__ h, const int* __restrict__ batch,
                                                const float* __restrict__ sum, const float* __restrict__ sumsq,
                                                const int* __restrict__ cnt, const float* __restrict__ w,
                                                const float* __restrict__ b, const float* __restrict__ ms,
                                                int logC, __half* __restrict__ h16) {
    int C = 1 << logC;
    int i = blockIdx.x * 256 + threadIdx.x;
    if (i >= NN * C) return;
    int nd = i >> logC, c = i & (C - 1);
    int g = batch[nd];
    float cg = fmaxf((float)cnt[g], 1.f);
    float mu = sum[g * C + c] / cg;
    float ex2 = sumsq[g * C + c] / cg;
    float s_ = ms[c];
    float var = ex2 - (2.f * s_ - s_ * s_) * mu * mu;
    float y = (h[i] - mu * s_) * rsqrtf(var + 1e-5f) * w[c] + b[c];
    y = fmaxf(y, 0.f);   // fused ReLU
    h[i] = y;
    if (h16) h16[i] = __float2half(y);
}

// ---------------- layer-3 head mean + bias ----------------

__global__ __launch_bounds__(256) void k_headmean(const float* __restrict__ tmp, const float* __restrict__ b3,
                                                  float* __restrict__ out) {
    int i = blockIdx.x * 256 + threadIdx.x;
    if (i >= NN * 8) return;
    int nd = i >> 3, c = i & 7;
    const float* p = tmp + (size_t)nd * 32 + c;
    out[i] = 0.25f * (p[0] + p[8] + p[16] + p[24]) + b3[c];
}

// ---------------- pool mean + linear head ----------------

__global__ __launch_bounds__(512) void k_final(const float* __restrict__ pool, const int* __restrict__ cnt,
                                               const float* __restrict__ lw, const float* __restrict__ lb,
                                               float* __restrict__ outp) {
    __shared__ float feat[512];
    int t = threadIdx.x;
    int g = t >> 3;
    float f = pool[t] / fmaxf((float)cnt[g], 1.f);
    feat[t] = f;
    outp[256 + t] = f;          // features: d_out[256 .. 768)
    __syncthreads();
    if (t < 256) {
        int g2 = t >> 2, o = t & 3;
        float a = lb[o];
#pragma unroll
        for (int cc = 0; cc < 8; ++cc) a += feat[g2 * 8 + cc] * lw[cc * 4 + o];
        outp[t] = a;            // logits: d_out[0 .. 256)
    }
}

// ---------------- host ----------------

extern "C" void kernel_launch(void* const* d_in, const int* in_sizes, int n_in,
                              void* d_out, int out_size, void* d_ws, size_t ws_size,
                              hipStream_t stream) {
    const float* x    = (const float*)d_in[0];
    const int*   ei   = (const int*)d_in[1];
    const int*   batch= (const int*)d_in[2];
    const float *w_l1 = (const float*)d_in[3],  *w_r1 = (const float*)d_in[4];
    const float *att1 = (const float*)d_in[5],  *b1   = (const float*)d_in[6];
    const float *gn1w = (const float*)d_in[7],  *gn1b = (const float*)d_in[8],  *gn1s = (const float*)d_in[9];
    const float *w_l2 = (const float*)d_in[10], *w_r2 = (const float*)d_in[11];
    const float *att2 = (const float*)d_in[12], *b2   = (const float*)d_in[13];
    const float *gn2w = (const float*)d_in[14], *gn2b = (const float*)d_in[15], *gn2s = (const float*)d_in[16];
    const float *w_l3 = (const float*)d_in[17], *w_r3 = (const float*)d_in[18];
    const float *att3 = (const float*)d_in[19], *b3   = (const float*)d_in[20];
    const float *gn3w = (const float*)d_in[21], *gn3b = (const float*)d_in[22], *gn3s = (const float*)d_in[23];
    const float *lw   = (const float*)d_in[24], *lb   = (const float*)d_in[25];

    char* ws = (char*)d_ws;
    size_t off = 0;
    auto alloc = [&](size_t bytes) -> void* {
        void* p = ws + off;
        off += (bytes + 255) & ~(size_t)255;
        return p;
    };
    __half* Ah  = (__half*)alloc((size_t)NN * 128 * 2);  // x_l fp16 (GEMM out, attn gather operand)
    __half* Xh  = (__half*)alloc((size_t)NN * 128 * 2);  // GEMM fp16 input (cast of x / gnnorm out)
    float*  B   = (float*)alloc((size_t)NN * 128 * 4);   // x_r / layer-out scratch
    float*  Cb  = (float*)alloc((size_t)NN * 64 * 4);    // h2 scratch
    float*  Af  = (float*)alloc((size_t)NN * 8 * 4);     // layer-3 final node features
    int* rowptr = (int*)alloc((size_t)(NN + 1) * 4);
    int* cursor = (int*)alloc((size_t)NN * 4);
    int* colsrc = (int*)alloc((size_t)ET * 4);
    int* bpos   = (int*)alloc((size_t)(NG + 1) * 4);
    int* cnt    = (int*)alloc((size_t)NG * 4);
    int* bsum   = (int*)alloc((size_t)NB * 4);
    int* boff   = (int*)alloc((size_t)NB * 4);
    char* zbase = ws + off;                              // everything below gets one memset
    int*   deg  = (int*)alloc((size_t)NN * 4);
    float* sum1 = (float*)alloc((size_t)NG * 128 * 4);
    float* sq1  = (float*)alloc((size_t)NG * 128 * 4);
    float* sum2 = (float*)alloc((size_t)NG * 64 * 4);
    float* sq2  = (float*)alloc((size_t)NG * 64 * 4);
    float* sum3 = (float*)alloc((size_t)NG * 8 * 4);
    float* sq3  = (float*)alloc((size_t)NG * 8 * 4);
    float* pool = (float*)alloc((size_t)NG * 8 * 4);
    size_t zbytes = (size_t)((ws + off) - zbase);
    hipMemsetAsync(zbase, 0, zbytes, stream);

    int gE = (ET + 255) / 256;
    k_cast<<<(NN * 128 / 8 + 255) / 256, 256, 0, stream>>>(x, Xh);
    k_count<<<gE, 256, 0, stream>>>(ei, deg);
    k_bounds<<<(NN + 255) / 256, 256, 0, stream>>>(batch, bpos);
    k_cnt<<<1, 64, 0, stream>>>(bpos, cnt);
    k_blksum<<<NB, 256, 0, stream>>>(deg, bsum);
    k_scanb<<<1, 256, 0, stream>>>(bsum, boff);
    k_scanc<<<NB, 256, 0, stream>>>(deg, boff, rowptr, cursor);
    k_scatter<<<gE, 256, 0, stream>>>(ei, cursor, colsrc);

    int gA4 = (NN * H * 4) / 256;            // attention grid, EP=4 -> 3125 blocks exact
    int gG  = (NN + 63) / 64;                // gn-reduce grid, 64 nodes/block

    // ---- layer 1: 128 -> 4x32 concat -> 128
    k_dualgemm<128, 128, 2><<<(NN + 31) / 32, 256, 0, stream>>>(Xh, w_l1, w_r1, Ah, B);
    k_attn<32, 4, true><<<gA4, 256, 0, stream>>>(Ah, B, rowptr, colsrc, att1, b1, B);
    k_gnred<7><<<gG, 256, 0, stream>>>(B, batch, sum1, sq1);
    k_gnnorm<<<(NN * 128 + 255) / 256, 256, 0, stream>>>(B, batch, sum1, sq1, cnt, gn1w, gn1b, gn1s, 7, Xh);

    // ---- layer 2: 128 -> 4x16 concat -> 64
    k_dualgemm<128, 64, 1><<<(NN + 63) / 64, 256, 0, stream>>>(Xh, w_l2, w_r2, Ah, Cb);
    k_attn<16, 4, true><<<gA4, 256, 0, stream>>>(Ah, Cb, rowptr, colsrc, att2, b2, Cb);
    k_gnred<6><<<gG, 256, 0, stream>>>(Cb, batch, sum2, sq2);
    k_gnnorm<<<(NN * 64 + 255) / 256, 256, 0, stream>>>(Cb, batch, sum2, sq2, cnt, gn2w, gn2b, gn2s, 6, Xh);

    // ---- layer 3: 64 -> 4x8 mean -> 8
    k_dualgemm<64, 32, 1><<<(NN + 63) / 64, 256, 0, stream>>>(Xh, w_l3, w_r3, Ah, B);
    k_attn<8, 4, false><<<gA4, 256, 0, stream>>>(Ah, B, rowptr, colsrc, att3, nullptr, B);
    k_headmean<<<(NN * 8 + 255) / 256, 256, 0, stream>>>(B, b3, Af);
    k_gnred<3><<<gG, 256, 0, stream>>>(Af, batch, sum3, sq3);
    k_gnnorm<<<(NN * 8 + 255) / 256, 256, 0, stream>>>(Af, batch, sum3, sq3, cnt, gn3w, gn3b, gn3s, 3, nullptr);

    // ---- global mean pool + linear
    k_gnred<3><<<gG, 256, 0, stream>>>(Af, batch, pool, sq3);  // sq3 as throwaway sumsq
    k_final<<<1, 512, 0, stream>>>(pool, cnt, lw, lb, (float*)d_out);
}

// Round 7
// 512.652 us; speedup vs baseline: 2.1493x; 1.0646x over previous
//
#include <hip/hip_runtime.h>
#include <hip/hip_fp16.h>
#include <math.h>

#define NN 50000
#define NE 800000
#define ET (NE + NN)
#define NG 64
#define H 4
#define NB ((NN + 255) / 256)   // 196 blocks of 256 nodes

typedef _Float16 half8 __attribute__((ext_vector_type(8)));
typedef float floatx4 __attribute__((ext_vector_type(4)));

// ---------------- CSR build ----------------

__global__ __launch_bounds__(256) void k_count(const int* __restrict__ ei, int* __restrict__ deg) {
    int e = blockIdx.x * 256 + threadIdx.x;
    if (e >= ET) return;
    int d = (e < NE) ? ei[NE + e] : (e - NE);
    atomicAdd(&deg[d], 1);
}

// batch is sorted: graph boundaries without atomics.
__global__ __launch_bounds__(256) void k_bounds(const int* __restrict__ batch, int* __restrict__ bpos) {
    int i = blockIdx.x * 256 + threadIdx.x;
    if (i >= NN) return;
    int cur = batch[i];
    int prev = (i == 0) ? -1 : batch[i - 1];
    for (int g = prev + 1; g <= cur; ++g) bpos[g] = i;
    if (i == NN - 1)
        for (int g = cur + 1; g <= NG; ++g) bpos[g] = NN;
}

__global__ __launch_bounds__(64) void k_cnt(const int* __restrict__ bpos, int* __restrict__ cnt) {
    int g = threadIdx.x;
    if (g < NG) cnt[g] = bpos[g + 1] - bpos[g];
}

// ---- decoupled 3-pass exclusive scan of deg[] -> rowptr/cursor

__global__ __launch_bounds__(256) void k_blksum(const int* __restrict__ deg, int* __restrict__ bsum) {
    int i = blockIdx.x * 256 + threadIdx.x;
    int v = (i < NN) ? deg[i] : 0;
    for (int off = 32; off; off >>= 1) v += __shfl_down(v, off, 64);
    __shared__ int lds[4];
    int lane = threadIdx.x & 63, wid = threadIdx.x >> 6;
    if (lane == 0) lds[wid] = v;
    __syncthreads();
    if (threadIdx.x == 0) bsum[blockIdx.x] = lds[0] + lds[1] + lds[2] + lds[3];
}

__global__ __launch_bounds__(256) void k_scanb(const int* __restrict__ bsum, int* __restrict__ boff) {
    __shared__ int lds[256];
    int t = threadIdx.x;
    int v = (t < NB) ? bsum[t] : 0;
    lds[t] = v;
    __syncthreads();
    for (int off = 1; off < 256; off <<= 1) {
        int y = (t >= off) ? lds[t - off] : 0;
        __syncthreads();
        lds[t] += y;
        __syncthreads();
    }
    if (t < NB) boff[t] = lds[t] - v;   // exclusive
}

__global__ __launch_bounds__(256) void k_scanc(const int* __restrict__ deg, const int* __restrict__ boff,
                                               int* __restrict__ rowptr, int* __restrict__ cursor) {
    int b = blockIdx.x, t = threadIdx.x;
    int i = b * 256 + t;
    int v = (i < NN) ? deg[i] : 0;
    int lane = t & 63, wid = t >> 6;
    int x = v;
    for (int off = 1; off < 64; off <<= 1) {
        int y = __shfl_up(x, off, 64);
        if (lane >= off) x += y;
    }
    __shared__ int wsum[4];
    if (lane == 63) wsum[wid] = x;
    __syncthreads();
    int base = boff[b];
    for (int w = 0; w < wid; ++w) base += wsum[w];
    int p = base + x - v;   // exclusive prefix for node i
    if (i < NN) { rowptr[i] = p; cursor[i] = p; }
    if (i == NN - 1) rowptr[NN] = p + v;
}

__global__ __launch_bounds__(256) void k_scatter(const int* __restrict__ ei, int* __restrict__ cursor,
                                                 unsigned short* __restrict__ colsrc) {
    int e = blockIdx.x * 256 + threadIdx.x;
    if (e >= ET) return;
    int s, d;
    if (e < NE) { s = ei[e]; d = ei[NE + e]; } else { s = e - NE; d = s; }
    int pos = atomicAdd(&cursor[d], 1);
    colsrc[pos] = (unsigned short)s;
}

// ---------------- fp32 -> fp16 cast (layer-1 GEMM input) ----------------

__global__ __launch_bounds__(256) void k_cast(const float* __restrict__ x, __half* __restrict__ xh) {
    int i = blockIdx.x * 256 + threadIdx.x;       // one thread = 8 elements; NN*128 % 8 == 0
    size_t base = (size_t)i * 8;
    if (base >= (size_t)NN * 128) return;
    const float4* p = (const float4*)(x + base);
    float4 a = p[0], b = p[1];
    half8 h;
    h[0] = (_Float16)a.x; h[1] = (_Float16)a.y; h[2] = (_Float16)a.z; h[3] = (_Float16)a.w;
    h[4] = (_Float16)b.x; h[5] = (_Float16)b.y; h[6] = (_Float16)b.z; h[7] = (_Float16)b.w;
    *(half8*)(xh + base) = h;
}

// ---------------- weight prep: fp32 [K][M2]x2 -> fp16 MFMA-fragment order ----------------
// chunk = (kt*NT + t)*64 + lane holds B-frag elements (n = t*16 + lane&15, k = kt*32 + (lane>>4)*8 + j).

template <int K, int M2>
__global__ __launch_bounds__(256) void k_wprep(const float* __restrict__ Wl, const float* __restrict__ Wr,
                                               _Float16* __restrict__ Wfrag) {
    constexpr int MTOT = 2 * M2, NT = MTOT / 16;
    int chunk = blockIdx.x * 256 + threadIdx.x;
    if (chunk >= MTOT * K / 8) return;
    int lane = chunk & 63, tt = chunk >> 6;
    int t = tt % NT, kt = tt / NT;
    int n = t * 16 + (lane & 15);
    int kb = kt * 32 + (lane >> 4) * 8;
    const float* src = (n < M2) ? (Wl + n) : (Wr + (n - M2));
    half8 h;
#pragma unroll
    for (int j = 0; j < 8; ++j) h[j] = (_Float16)src[(size_t)(kb + j) * M2];
    *(half8*)(Wfrag + (size_t)chunk * 8) = h;
}

// ---------------- fused dual MFMA GEMM, LDS-free ----------------
// O_l[NN,M2] (fp16) = A @ Wl ; O_r[NN,M2] (fp32) = A @ Wr. A fp16 [NN,K] row-major.
// B-fragments stream from frag-ordered global Wfrag (<=64KB, L2-resident, perfectly coalesced).
// Block = 64 rows (4 waves x 16). D layout: col=lane&15, row=(lane>>4)*4+reg (verified r6).

template <int K, int M2>
__global__ __launch_bounds__(256) void k_dualgemm(const __half* __restrict__ Ain,
                                                  const _Float16* __restrict__ Wfrag,
                                                  __half* __restrict__ Ol, float* __restrict__ Or) {
    constexpr int MTOT = 2 * M2;
    constexpr int NT = MTOT / 16;
    constexpr int KT = K / 32;
    int tid = threadIdx.x;
    int wid = tid >> 6, lane = tid & 63;
    int q = lane >> 4, l15 = lane & 15;
    int r0 = blockIdx.x * 64 + wid * 16;
    int arow = min(r0 + l15, NN - 1);
    const _Float16* A = (const _Float16*)Ain;
    const _Float16* ap = A + (size_t)arow * K + q * 8;

    floatx4 acc[NT];
#pragma unroll
    for (int t = 0; t < NT; ++t) acc[t] = (floatx4){0.f, 0.f, 0.f, 0.f};

#pragma unroll
    for (int kt = 0; kt < KT; ++kt) {
        half8 a8 = *(const half8*)(ap + kt * 32);
        const _Float16* wp = Wfrag + ((size_t)(kt * NT) * 64 + lane) * 8;
#pragma unroll
        for (int t = 0; t < NT; ++t) {
            half8 b8 = *(const half8*)(wp + (size_t)t * 64 * 8);
            acc[t] = __builtin_amdgcn_mfma_f32_16x16x32_f16(a8, b8, acc[t], 0, 0, 0);
        }
    }

#pragma unroll
    for (int t = 0; t < NT; ++t) {
        int cn = t * 16 + l15;
#pragma unroll
        for (int reg = 0; reg < 4; ++reg) {
            int r = r0 + q * 4 + reg;
            if (r < NN) {
                if (cn < M2) Ol[(size_t)r * M2 + cn] = __float2half(acc[t][reg]);
                else         Or[(size_t)r * M2 + (cn - M2)] = acc[t][reg];
            }
        }
    }
}

// ---------------- GATv2 attention: channel-split, EP lanes cooperate per (node,head) ----------------

template <int CP>
__device__ __forceinline__ void load_h16(const __half* __restrict__ p, float* __restrict__ xv) {
    if constexpr (CP == 8) {
        float4 r = *(const float4*)p;
        const __half2* hp = (const __half2*)&r;
#pragma unroll
        for (int j = 0; j < 4; ++j) {
            float2 f = __half22float2(hp[j]);
            xv[2 * j] = f.x; xv[2 * j + 1] = f.y;
        }
    } else if constexpr (CP == 4) {
        float2 r = *(const float2*)p;
        const __half2* hp = (const __half2*)&r;
#pragma unroll
        for (int j = 0; j < 2; ++j) {
            float2 f = __half22float2(hp[j]);
            xv[2 * j] = f.x; xv[2 * j + 1] = f.y;
        }
    } else {
        __half2 r = *(const __half2*)p;
        float2 f = __half22float2(r);
        xv[0] = f.x; xv[1] = f.y;
    }
}

template <int C, int EP, bool CONCAT>
__global__ __launch_bounds__(256, 4) void k_attn(const __half* __restrict__ xl, const float* __restrict__ xr,
                                                 const int* __restrict__ rowptr,
                                                 const unsigned short* __restrict__ colsrc,
                                                 const float* __restrict__ att, const float* __restrict__ bias,
                                                 float* __restrict__ out) {
    constexpr int CP = C / EP;
    int t = blockIdx.x * 256 + threadIdx.x;
    int part = t & (EP - 1);
    int nh = t >> 2;                          // EP == 4
    if (nh >= NN * H) return;
    int node = nh >> 2, h = nh & 3;           // H == 4
    int cbase = h * C + part * CP;
    float xrr[CP], attv[CP], acc[CP];
    {
        const float* p = xr + (size_t)node * (H * C) + cbase;
        const float* q = att + cbase;
#pragma unroll
        for (int c = 0; c < CP; ++c) { xrr[c] = p[c]; attv[c] = q[c]; acc[c] = 0.f; }
    }
    float m = -1e30f, denom = 0.f;
    int beg = rowptr[node], end = rowptr[node + 1];

    auto process = [&](const float* __restrict__ xv) {
        float part_s = 0.f;
#pragma unroll
        for (int c = 0; c < CP; ++c) {
            float z = xv[c] + xrr[c];
            z = (z > 0.f) ? z : 0.2f * z;     // leaky_relu slope 0.2
            part_s += attv[c] * z;
        }
        float score = part_s;
#pragma unroll
        for (int mask = 1; mask < EP; mask <<= 1) score += __shfl_xor(score, mask, 64);
        float mn = fmaxf(m, score);
        float es = __expf(m - mn);
        float w = __expf(score - mn);
        denom = denom * es + w;
#pragma unroll
        for (int c = 0; c < CP; ++c) acc[c] = acc[c] * es + w * xv[c];
        m = mn;
    };

    int idx = beg;
    for (; idx + 2 <= end; idx += 2) {
        int s0 = colsrc[idx], s1 = colsrc[idx + 1];
        float xv0[CP], xv1[CP];
        load_h16<CP>(xl + (size_t)s0 * (H * C) + cbase, xv0);
        load_h16<CP>(xl + (size_t)s1 * (H * C) + cbase, xv1);
        process(xv0);
        process(xv1);
    }
    if (idx < end) {
        int s = colsrc[idx];
        float xv[CP];
        load_h16<CP>(xl + (size_t)s * (H * C) + cbase, xv);
        process(xv);
    }

    float inv = 1.f / denom;
    float* op = out + (size_t)node * (H * C) + cbase;
    float v[CP];
#pragma unroll
    for (int c = 0; c < CP; ++c) {
        v[c] = acc[c] * inv;
        if (CONCAT) v[c] += bias[cbase + c];
    }
    if constexpr (CP == 8) {
        *(float4*)(op) = make_float4(v[0], v[1], v[2], v[3]);
        *(float4*)(op + 4) = make_float4(v[4], v[5], v[6], v[7]);
    } else if constexpr (CP == 4) {
        *(float4*)(op) = make_float4(v[0], v[1], v[2], v[3]);
    } else {
        *(float2*)(op) = make_float2(v[0], v[1]);
    }
}

// ---------------- GraphNorm ----------------
// 64 nodes/block, compile-time trip counts -> unrolled, loads batched; run-length flush.

template <int LOGC>
__global__ __launch_bounds__(256) void k_gnred(const float* __restrict__ h, const int* __restrict__ batch,
                                               float* __restrict__ sum, float* __restrict__ sumsq) {
    constexpr int C = 1 << LOGC;
    constexpr int ROWS = 256 >> LOGC;
    constexpr int NPB = 64;
    int c = threadIdx.x & (C - 1);
    int row = threadIdx.x >> LOGC;
    int base = blockIdx.x * NPB;
    int curg = -1;
    float s = 0.f, ss = 0.f;
#pragma unroll
    for (int r = row; r < NPB; r += ROWS) {
        int nd = base + r;
        if (nd >= NN) break;
        int g = batch[nd];
        if (g != curg) {
            if (curg >= 0) { atomicAdd(&sum[curg * C + c], s); atomicAdd(&sumsq[curg * C + c], ss); }
            curg = g; s = 0.f; ss = 0.f;
        }
        float x = h[(size_t)nd * C + c];
        s += x; ss += x * x;
    }
    if (curg >= 0) { atomicAdd(&sum[curg * C + c], s); atomicAdd(&sumsq[curg * C + c], ss); }
}

// var(out) = E[x^2] - (2s - s^2) mu^2  where out = x - mu*s; optional fp16 copy for next GEMM
__global__ __launch_bounds__(256) void k_gnnorm(float* __restrict__ h, const int* __restrict__ batch,
                                                const float* __restrict__ sum, const float* __restrict__ sumsq,
                                                const int* __restrict__ cnt, const float* __restrict__ w,
                                                const float* __restrict__ b, const float* __restrict__ ms,
                                                int logC, __half* __restrict__ h16) {
    int C = 1 << logC;
    int i = blockIdx.x * 256 + threadIdx.x;
    if (i >= NN * C) return;
    int nd = i >> logC, c = i & (C - 1);
    int g = batch[nd];
    float cg = fmaxf((float)cnt[g], 1.f);
    float mu = sum[g * C + c] / cg;
    float ex2 = sumsq[g * C + c] / cg;
    float s_ = ms[c];
    float var = ex2 - (2.f * s_ - s_ * s_) * mu * mu;
    float y = (h[i] - mu * s_) * rsqrtf(var + 1e-5f) * w[c] + b[c];
    y = fmaxf(y, 0.f);   // fused ReLU
    h[i] = y;
    if (h16) h16[i] = __float2half(y);
}

// ---------------- layer-3 head mean + bias ----------------

__global__ __launch_bounds__(256) void k_headmean(const float* __restrict__ tmp, const float* __restrict__ b3,
                                                  float* __restrict__ out) {
    int i = blockIdx.x * 256 + threadIdx.x;
    if (i >= NN * 8) return;
    int nd = i >> 3, c = i & 7;
    const float* p = tmp + (size_t)nd * 32 + c;
    out[i] = 0.25f * (p[0] + p[8] + p[16] + p[24]) + b3[c];
}

// ---------------- pool mean + linear head ----------------

__global__ __launch_bounds__(512) void k_final(const float* __restrict__ pool, const int* __restrict__ cnt,
                                               const float* __restrict__ lw, const float* __restrict__ lb,
                                               float* __restrict__ outp) {
    __shared__ float feat[512];
    int t = threadIdx.x;
    int g = t >> 3;
    float f = pool[t] / fmaxf((float)cnt[g], 1.f);
    feat[t] = f;
    outp[256 + t] = f;          // features: d_out[256 .. 768)
    __syncthreads();
    if (t < 256) {
        int g2 = t >> 2, o = t & 3;
        float a = lb[o];
#pragma unroll
        for (int cc = 0; cc < 8; ++cc) a += feat[g2 * 8 + cc] * lw[cc * 4 + o];
        outp[t] = a;            // logits: d_out[0 .. 256)
    }
}

// ---------------- host ----------------

extern "C" void kernel_launch(void* const* d_in, const int* in_sizes, int n_in,
                              void* d_out, int out_size, void* d_ws, size_t ws_size,
                              hipStream_t stream) {
    const float* x    = (const float*)d_in[0];
    const int*   ei   = (const int*)d_in[1];
    const int*   batch= (const int*)d_in[2];
    const float *w_l1 = (const float*)d_in[3],  *w_r1 = (const float*)d_in[4];
    const float *att1 = (const float*)d_in[5],  *b1   = (const float*)d_in[6];
    const float *gn1w = (const float*)d_in[7],  *gn1b = (const float*)d_in[8],  *gn1s = (const float*)d_in[9];
    const float *w_l2 = (const float*)d_in[10], *w_r2 = (const float*)d_in[11];
    const float *att2 = (const float*)d_in[12], *b2   = (const float*)d_in[13];
    const float *gn2w = (const float*)d_in[14], *gn2b = (const float*)d_in[15], *gn2s = (const float*)d_in[16];
    const float *w_l3 = (const float*)d_in[17], *w_r3 = (const float*)d_in[18];
    const float *att3 = (const float*)d_in[19], *b3   = (const float*)d_in[20];
    const float *gn3w = (const float*)d_in[21], *gn3b = (const float*)d_in[22], *gn3s = (const float*)d_in[23];
    const float *lw   = (const float*)d_in[24], *lb   = (const float*)d_in[25];

    char* ws = (char*)d_ws;
    size_t off = 0;
    auto alloc = [&](size_t bytes) -> void* {
        void* p = ws + off;
        off += (bytes + 255) & ~(size_t)255;
        return p;
    };
    __half* Ah  = (__half*)alloc((size_t)NN * 128 * 2);  // x_l fp16 (GEMM out, attn gather operand)
    __half* Xh  = (__half*)alloc((size_t)NN * 128 * 2);  // GEMM fp16 input (cast of x / gnnorm out)
    float*  B   = (float*)alloc((size_t)NN * 128 * 4);   // x_r / layer-out scratch
    float*  Cb  = (float*)alloc((size_t)NN * 64 * 4);    // h2 scratch
    float*  Af  = (float*)alloc((size_t)NN * 8 * 4);     // layer-3 final node features
    _Float16* Wf1 = (_Float16*)alloc((size_t)256 * 128 * 2);  // frag-ordered weights l1
    _Float16* Wf2 = (_Float16*)alloc((size_t)128 * 128 * 2);  // l2
    _Float16* Wf3 = (_Float16*)alloc((size_t)64 * 64 * 2);    // l3
    int* rowptr = (int*)alloc((size_t)(NN + 1) * 4);
    int* cursor = (int*)alloc((size_t)NN * 4);
    unsigned short* colsrc = (unsigned short*)alloc((size_t)ET * 2);
    int* bpos   = (int*)alloc((size_t)(NG + 1) * 4);
    int* cnt    = (int*)alloc((size_t)NG * 4);
    int* bsum   = (int*)alloc((size_t)NB * 4);
    int* boff   = (int*)alloc((size_t)NB * 4);
    char* zbase = ws + off;                              // everything below gets one memset
    int*   deg  = (int*)alloc((size_t)NN * 4);
    float* sum1 = (float*)alloc((size_t)NG * 128 * 4);
    float* sq1  = (float*)alloc((size_t)NG * 128 * 4);
    float* sum2 = (float*)alloc((size_t)NG * 64 * 4);
    float* sq2  = (float*)alloc((size_t)NG * 64 * 4);
    float* sum3 = (float*)alloc((size_t)NG * 8 * 4);
    float* sq3  = (float*)alloc((size_t)NG * 8 * 4);
    float* pool = (float*)alloc((size_t)NG * 8 * 4);
    size_t zbytes = (size_t)((ws + off) - zbase);
    hipMemsetAsync(zbase, 0, zbytes, stream);

    int gE = (ET + 255) / 256;
    k_cast<<<(NN * 128 / 8 + 255) / 256, 256, 0, stream>>>(x, Xh);
    k_wprep<128, 128><<<(256 * 128 / 8 + 255) / 256, 256, 0, stream>>>(w_l1, w_r1, Wf1);
    k_wprep<128, 64><<<(128 * 128 / 8 + 255) / 256, 256, 0, stream>>>(w_l2, w_r2, Wf2);
    k_wprep<64, 32><<<(64 * 64 / 8 + 255) / 256, 256, 0, stream>>>(w_l3, w_r3, Wf3);
    k_count<<<gE, 256, 0, stream>>>(ei, deg);
    k_bounds<<<(NN + 255) / 256, 256, 0, stream>>>(batch, bpos);
    k_cnt<<<1, 64, 0, stream>>>(bpos, cnt);
    k_blksum<<<NB, 256, 0, stream>>>(deg, bsum);
    k_scanb<<<1, 256, 0, stream>>>(bsum, boff);
    k_scanc<<<NB, 256, 0, stream>>>(deg, boff, rowptr, cursor);
    k_scatter<<<gE, 256, 0, stream>>>(ei, cursor, colsrc);

    int gA4 = (NN * H * 4) / 256;            // attention grid, EP=4 -> 3125 blocks exact
    int gG  = (NN + 63) / 64;                // gn-reduce grid, 64 nodes/block
    int gD  = (NN + 63) / 64;                // dualgemm grid, 64 rows/block

    // ---- layer 1: 128 -> 4x32 concat -> 128
    k_dualgemm<128, 128><<<gD, 256, 0, stream>>>(Xh, Wf1, Ah, B);
    k_attn<32, 4, true><<<gA4, 256, 0, stream>>>(Ah, B, rowptr, colsrc, att1, b1, B);
    k_gnred<7><<<gG, 256, 0, stream>>>(B, batch, sum1, sq1);
    k_gnnorm<<<(NN * 128 + 255) / 256, 256, 0, stream>>>(B, batch, sum1, sq1, cnt, gn1w, gn1b, gn1s, 7, Xh);

    // ---- layer 2: 128 -> 4x16 concat -> 64
    k_dualgemm<128, 64><<<gD, 256, 0, stream>>>(Xh, Wf2, Ah, Cb);
    k_attn<16, 4, true><<<gA4, 256, 0, stream>>>(Ah, Cb, rowptr, colsrc, att2, b2, Cb);
    k_gnred<6><<<gG, 256, 0, stream>>>(Cb, batch, sum2, sq2);
    k_gnnorm<<<(NN * 64 + 255) / 256, 256, 0, stream>>>(Cb, batch, sum2, sq2, cnt, gn2w, gn2b, gn2s, 6, Xh);

    // ---- layer 3: 64 -> 4x8 mean -> 8
    k_dualgemm<64, 32><<<gD, 256, 0, stream>>>(Xh, Wf3, Ah, B);
    k_attn<8, 4, false><<<gA4, 256, 0, stream>>>(Ah, B, rowptr, colsrc, att3, nullptr, B);
    k_headmean<<<(NN * 8 + 255) / 256, 256, 0, stream>>>(B, b3, Af);
    k_gnred<3><<<gG, 256, 0, stream>>>(Af, batch, sum3, sq3);
    k_gnnorm<<<(NN * 8 + 255) / 256, 256, 0, stream>>>(Af, batch, sum3, sq3, cnt, gn3w, gn3b, gn3s, 3, nullptr);

    // ---- global mean pool + linear
    k_gnred<3><<<gG, 256, 0, stream>>>(Af, batch, pool, sq3);  // sq3 as throwaway sumsq
    k_final<<<1, 512, 0, stream>>>(pool, cnt, lw, lb, (float*)d_out);
}

// Round 9
// 503.567 us; speedup vs baseline: 2.1881x; 1.0180x over previous
//
#include <hip/hip_runtime.h>
#include <hip/hip_fp16.h>
#include <math.h>

#define NN 50000
#define NE 800000
#define ET (NE + NN)
#define NG 64
#define H 4
#define NB ((NN + 255) / 256)   // 196 blocks of 256 nodes

typedef _Float16 half8 __attribute__((ext_vector_type(8)));
typedef _Float16 hv2 __attribute__((ext_vector_type(2)));
typedef float floatx4 __attribute__((ext_vector_type(4)));

// ---------------- CSR build ----------------

__global__ __launch_bounds__(256) void k_count(const int* __restrict__ ei, int* __restrict__ deg) {
    int e = blockIdx.x * 256 + threadIdx.x;
    if (e >= ET) return;
    int d = (e < NE) ? ei[NE + e] : (e - NE);
    atomicAdd(&deg[d], 1);
}

// batch is sorted: graph boundaries without atomics.
__global__ __launch_bounds__(256) void k_bounds(const int* __restrict__ batch, int* __restrict__ bpos) {
    int i = blockIdx.x * 256 + threadIdx.x;
    if (i >= NN) return;
    int cur = batch[i];
    int prev = (i == 0) ? -1 : batch[i - 1];
    for (int g = prev + 1; g <= cur; ++g) bpos[g] = i;
    if (i == NN - 1)
        for (int g = cur + 1; g <= NG; ++g) bpos[g] = NN;
}

// ---- decoupled 3-pass exclusive scan of deg[] -> rowptr/cursor

__global__ __launch_bounds__(256) void k_blksum(const int* __restrict__ deg, int* __restrict__ bsum) {
    int i = blockIdx.x * 256 + threadIdx.x;
    int v = (i < NN) ? deg[i] : 0;
    for (int off = 32; off; off >>= 1) v += __shfl_down(v, off, 64);
    __shared__ int lds[4];
    int lane = threadIdx.x & 63, wid = threadIdx.x >> 6;
    if (lane == 0) lds[wid] = v;
    __syncthreads();
    if (threadIdx.x == 0) bsum[blockIdx.x] = lds[0] + lds[1] + lds[2] + lds[3];
}

// scan of block sums; also derives per-graph counts from bpos (folded k_cnt)
__global__ __launch_bounds__(256) void k_scanb(const int* __restrict__ bsum, int* __restrict__ boff,
                                               const int* __restrict__ bpos, int* __restrict__ cnt) {
    __shared__ int lds[256];
    int t = threadIdx.x;
    int v = (t < NB) ? bsum[t] : 0;
    lds[t] = v;
    __syncthreads();
    for (int off = 1; off < 256; off <<= 1) {
        int y = (t >= off) ? lds[t - off] : 0;
        __syncthreads();
        lds[t] += y;
        __syncthreads();
    }
    if (t < NB) boff[t] = lds[t] - v;   // exclusive
    if (t < NG) cnt[t] = bpos[t + 1] - bpos[t];
}

__global__ __launch_bounds__(256) void k_scanc(const int* __restrict__ deg, const int* __restrict__ boff,
                                               int* __restrict__ rowptr, int* __restrict__ cursor) {
    int b = blockIdx.x, t = threadIdx.x;
    int i = b * 256 + t;
    int v = (i < NN) ? deg[i] : 0;
    int lane = t & 63, wid = t >> 6;
    int x = v;
    for (int off = 1; off < 64; off <<= 1) {
        int y = __shfl_up(x, off, 64);
        if (lane >= off) x += y;
    }
    __shared__ int wsum[4];
    if (lane == 63) wsum[wid] = x;
    __syncthreads();
    int base = boff[b];
    for (int w = 0; w < wid; ++w) base += wsum[w];
    int p = base + x - v;   // exclusive prefix for node i
    if (i < NN) { rowptr[i] = p; cursor[i] = p; }
    if (i == NN - 1) rowptr[NN] = p + v;
}

__global__ __launch_bounds__(256) void k_scatter(const int* __restrict__ ei, int* __restrict__ cursor,
                                                 unsigned short* __restrict__ colsrc) {
    int e = blockIdx.x * 256 + threadIdx.x;
    if (e >= ET) return;
    int s, d;
    if (e < NE) { s = ei[e]; d = ei[NE + e]; } else { s = e - NE; d = s; }
    int pos = atomicAdd(&cursor[d], 1);
    colsrc[pos] = (unsigned short)s;
}

// ---------------- fp32 -> fp16 cast (layer-1 GEMM input) ----------------

__global__ __launch_bounds__(256) void k_cast(const float* __restrict__ x, __half* __restrict__ xh) {
    int i = blockIdx.x * 256 + threadIdx.x;       // one thread = 8 elements; NN*128 % 8 == 0
    size_t base = (size_t)i * 8;
    if (base >= (size_t)NN * 128) return;
    const float4* p = (const float4*)(x + base);
    float4 a = p[0], b = p[1];
    half8 h;
    h[0] = (_Float16)a.x; h[1] = (_Float16)a.y; h[2] = (_Float16)a.z; h[3] = (_Float16)a.w;
    h[4] = (_Float16)b.x; h[5] = (_Float16)b.y; h[6] = (_Float16)b.z; h[7] = (_Float16)b.w;
    *(half8*)(xh + base) = h;
}

// ---------------- weight prep: fp32 [K][M2]x2 -> fp16 MFMA-fragment order (all 3 layers fused) ----------------

template <int K, int M2>
__device__ __forceinline__ void wprep_fn(int chunk, const float* __restrict__ Wl, const float* __restrict__ Wr,
                                         _Float16* __restrict__ Wfrag) {
    constexpr int MTOT = 2 * M2, NT = MTOT / 16;
    if (chunk >= MTOT * K / 8) return;
    int lane = chunk & 63, tt = chunk >> 6;
    int t = tt % NT, kt = tt / NT;
    int n = t * 16 + (lane & 15);
    int kb = kt * 32 + (lane >> 4) * 8;
    const float* src = (n < M2) ? (Wl + n) : (Wr + (n - M2));
    half8 h;
#pragma unroll
    for (int j = 0; j < 8; ++j) h[j] = (_Float16)src[(size_t)(kb + j) * M2];
    *(half8*)(Wfrag + (size_t)chunk * 8) = h;
}

__global__ __launch_bounds__(256) void k_wprep_all(const float* __restrict__ Wl1, const float* __restrict__ Wr1,
                                                   const float* __restrict__ Wl2, const float* __restrict__ Wr2,
                                                   const float* __restrict__ Wl3, const float* __restrict__ Wr3,
                                                   _Float16* __restrict__ Wf1, _Float16* __restrict__ Wf2,
                                                   _Float16* __restrict__ Wf3) {
    int b = blockIdx.x, t = threadIdx.x;
    if (b < 16)      wprep_fn<128, 128>(b * 256 + t, Wl1, Wr1, Wf1);
    else if (b < 24) wprep_fn<128, 64>((b - 16) * 256 + t, Wl2, Wr2, Wf2);
    else             wprep_fn<64, 32>((b - 24) * 256 + t, Wl3, Wr3, Wf3);
}

// ---------------- fused dual MFMA GEMM, LDS-free ----------------

template <int K, int M2>
__global__ __launch_bounds__(256) void k_dualgemm(const __half* __restrict__ Ain,
                                                  const _Float16* __restrict__ Wfrag,
                                                  __half* __restrict__ Ol, float* __restrict__ Or) {
    constexpr int MTOT = 2 * M2;
    constexpr int NT = MTOT / 16;
    constexpr int KT = K / 32;
    int tid = threadIdx.x;
    int wid = tid >> 6, lane = tid & 63;
    int q = lane >> 4, l15 = lane & 15;
    int r0 = blockIdx.x * 64 + wid * 16;
    int arow = min(r0 + l15, NN - 1);
    const _Float16* A = (const _Float16*)Ain;
    const _Float16* ap = A + (size_t)arow * K + q * 8;

    floatx4 acc[NT];
#pragma unroll
    for (int t = 0; t < NT; ++t) acc[t] = (floatx4){0.f, 0.f, 0.f, 0.f};

#pragma unroll
    for (int kt = 0; kt < KT; ++kt) {
        half8 a8 = *(const half8*)(ap + kt * 32);
        const _Float16* wp = Wfrag + ((size_t)(kt * NT) * 64 + lane) * 8;
#pragma unroll
        for (int t = 0; t < NT; ++t) {
            half8 b8 = *(const half8*)(wp + (size_t)t * 64 * 8);
            acc[t] = __builtin_amdgcn_mfma_f32_16x16x32_f16(a8, b8, acc[t], 0, 0, 0);
        }
    }

#pragma unroll
    for (int t = 0; t < NT; ++t) {
        int cn = t * 16 + l15;
#pragma unroll
        for (int reg = 0; reg < 4; ++reg) {
            int r = r0 + q * 4 + reg;
            if (r < NN) {
                if (cn < M2) Ol[(size_t)r * M2 + cn] = __float2half(acc[t][reg]);
                else         Or[(size_t)r * M2 + (cn - M2)] = acc[t][reg];
            }
        }
    }
}

// ---------------- GATv2 attention: channel-split + packed fp16 + no-max softmax ----------------
// Scores bounded (|score| << 88) -> exp(score) safe; max-subtraction is softmax-invariant so
// dropping it is exact. Packed path: v_pk_add_f16 / v_pk_max_f16 / v_dot2_f32_f16.

template <int CP> struct HVec { hv2 h2[CP / 2]; };

template <int CP>
__device__ __forceinline__ HVec<CP> load_hv(const __half* __restrict__ p) {
    HVec<CP> r;
    if constexpr (CP == 8) { float4 t = *(const float4*)p; r = *(HVec<CP>*)&t; }
    else if constexpr (CP == 4) { float2 t = *(const float2*)p; r = *(HVec<CP>*)&t; }
    else { r.h2[0] = *(const hv2*)p; }
    return r;
}

template <int C, int EP, bool CONCAT>
__global__ __launch_bounds__(256, 4) void k_attn(const __half* __restrict__ xl, const float* __restrict__ xr,
                                                 const int* __restrict__ rowptr,
                                                 const unsigned short* __restrict__ colsrc,
                                                 const float* __restrict__ att, const float* __restrict__ bias,
                                                 float* __restrict__ out) {
    constexpr int CP = C / EP;
    int t = blockIdx.x * 256 + threadIdx.x;
    int part = t & (EP - 1);
    int nh = t >> 2;                          // EP == 4
    if (nh >= NN * H) return;
    int node = nh >> 2, h = nh & 3;           // H == 4
    int cbase = h * C + part * CP;
    hv2 xrr2[CP / 2], attv2[CP / 2];
    float acc[CP];
    {
        const float* p = xr + (size_t)node * (H * C) + cbase;
        const float* q = att + cbase;
#pragma unroll
        for (int j = 0; j < CP / 2; ++j) {
            xrr2[j] = (hv2){(_Float16)p[2 * j], (_Float16)p[2 * j + 1]};
            attv2[j] = (hv2){(_Float16)q[2 * j], (_Float16)q[2 * j + 1]};
        }
#pragma unroll
        for (int c = 0; c < CP; ++c) acc[c] = 0.f;
    }
    float denom = 0.f;
    int beg = rowptr[node], end = rowptr[node + 1];

    auto process = [&](const HVec<CP>& xv) {
        float part_s = 0.f;
#pragma unroll
        for (int j = 0; j < CP / 2; ++j) {
            hv2 z = xv.h2[j] + xrr2[j];
            hv2 l = __builtin_elementwise_max(z, z * (_Float16)0.2f);   // leaky_relu
            part_s = __builtin_amdgcn_fdot2(l, attv2[j], part_s, false);
        }
        float score = part_s;
#pragma unroll
        for (int mask = 1; mask < EP; mask <<= 1) score += __shfl_xor(score, mask, 64);
        float w = __expf(score);
        denom += w;
        const _Float16* xh = (const _Float16*)&xv;
#pragma unroll
        for (int c = 0; c < CP; ++c) acc[c] = fmaf(w, (float)xh[c], acc[c]);
    };

    int idx = beg;
    for (; idx + 2 <= end; idx += 2) {
        int s0 = colsrc[idx], s1 = colsrc[idx + 1];
        HVec<CP> xv0 = load_hv<CP>(xl + (size_t)s0 * (H * C) + cbase);
        HVec<CP> xv1 = load_hv<CP>(xl + (size_t)s1 * (H * C) + cbase);
        process(xv0);
        process(xv1);
    }
    if (idx < end) {
        int s = colsrc[idx];
        HVec<CP> xv = load_hv<CP>(xl + (size_t)s * (H * C) + cbase);
        process(xv);
    }

    float inv = 1.f / denom;
    float* op = out + (size_t)node * (H * C) + cbase;
    float v[CP];
#pragma unroll
    for (int c = 0; c < CP; ++c) {
        v[c] = acc[c] * inv;
        if (CONCAT) v[c] += bias[cbase + c];
    }
    if constexpr (CP == 8) {
        *(float4*)(op) = make_float4(v[0], v[1], v[2], v[3]);
        *(float4*)(op + 4) = make_float4(v[4], v[5], v[6], v[7]);
    } else if constexpr (CP == 4) {
        *(float4*)(op) = make_float4(v[0], v[1], v[2], v[3]);
    } else {
        *(float2*)(op) = make_float2(v[0], v[1]);
    }
}

// ---------------- GraphNorm ----------------

template <int LOGC>
__global__ __launch_bounds__(256) void k_gnred(const float* __restrict__ h, const int* __restrict__ batch,
                                               float* __restrict__ sum, float* __restrict__ sumsq) {
    constexpr int C = 1 << LOGC;
    constexpr int ROWS = 256 >> LOGC;
    constexpr int NPB = 64;
    int c = threadIdx.x & (C - 1);
    int row = threadIdx.x >> LOGC;
    int base = blockIdx.x * NPB;
    int curg = -1;
    float s = 0.f, ss = 0.f;
#pragma unroll
    for (int r = row; r < NPB; r += ROWS) {
        int nd = base + r;
        if (nd >= NN) break;
        int g = batch[nd];
        if (g != curg) {
            if (curg >= 0) { atomicAdd(&sum[curg * C + c], s); atomicAdd(&sumsq[curg * C + c], ss); }
            curg = g; s = 0.f; ss = 0.f;
        }
        float x = h[(size_t)nd * C + c];
        s += x; ss += x * x;
    }
    if (curg >= 0) { atomicAdd(&sum[curg * C + c], s); atomicAdd(&sumsq[curg * C + c], ss); }
}

// var(out) = E[x^2] - (2s - s^2) mu^2  where out = x - mu*s; optional fp16 copy for next GEMM
__global__ __launch_bounds__(256) void k_gnnorm(float* __restrict__ h, const int* __restrict__ batch,
                                                const float* __restrict__ sum, const float* __restrict__ sumsq,
                                                const int* __restrict__ cnt, const float* __restrict__ w,
                                                const float* __restrict__ b, const float* __restrict__ ms,
                                                int logC, __half* __restrict__ h16) {
    int C = 1 << logC;
    int i = blockIdx.x * 256 + threadIdx.x;
    if (i >= NN * C) return;
    int nd = i >> logC, c = i & (C - 1);
    int g = batch[nd];
    float cg = fmaxf((float)cnt[g], 1.f);
    float mu = sum[g * C + c] / cg;
    float ex2 = sumsq[g * C + c] / cg;
    float s_ = ms[c];
    float var = ex2 - (2.f * s_ - s_ * s_) * mu * mu;
    float y = (h[i] - mu * s_) * rsqrtf(var + 1e-5f) * w[c] + b[c];
    y = fmaxf(y, 0.f);   // fused ReLU
    h[i] = y;
    if (h16) h16[i] = __float2half(y);
}

// ---------------- layer-3 head mean + bias ----------------

__global__ __launch_bounds__(256) void k_headmean(const float* __restrict__ tmp, const float* __restrict__ b3,
                                                  float* __restrict__ out) {
    int i = blockIdx.x * 256 + threadIdx.x;
    if (i >= NN * 8) return;
    int nd = i >> 3, c = i & 7;
    const float* p = tmp + (size_t)nd * 32 + c;
    out[i] = 0.25f * (p[0] + p[8] + p[16] + p[24]) + b3[c];
}

// ---------------- pool mean + linear head ----------------

__global__ __launch_bounds__(512) void k_final(const float* __restrict__ pool, const int* __restrict__ cnt,
                                               const float* __restrict__ lw, const float* __restrict__ lb,
                                               float* __restrict__ outp) {
    __shared__ float feat[512];
    int t = threadIdx.x;
    int g = t >> 3;
    float f = pool[t] / fmaxf((float)cnt[g], 1.f);
    feat[t] = f;
    outp[256 + t] = f;          // features: d_out[256 .. 768)
    __syncthreads();
    if (t < 256) {
        int g2 = t >> 2, o = t & 3;
        float a = lb[o];
#pragma unroll
        for (int cc = 0; cc < 8; ++cc) a += feat[g2 * 8 + cc] * lw[cc * 4 + o];
        outp[t] = a;            // logits: d_out[0 .. 256)
    }
}

// ---------------- host ----------------

extern "C" void kernel_launch(void* const* d_in, const int* in_sizes, int n_in,
                              void* d_out, int out_size, void* d_ws, size_t ws_size,
                              hipStream_t stream) {
    const float* x    = (const float*)d_in[0];
    const int*   ei   = (const int*)d_in[1];
    const int*   batch= (const int*)d_in[2];
    const float *w_l1 = (const float*)d_in[3],  *w_r1 = (const float*)d_in[4];
    const float *att1 = (const float*)d_in[5],  *b1   = (const float*)d_in[6];
    const float *gn1w = (const float*)d_in[7],  *gn1b = (const float*)d_in[8],  *gn1s = (const float*)d_in[9];
    const float *w_l2 = (const float*)d_in[10], *w_r2 = (const float*)d_in[11];
    const float *att2 = (const float*)d_in[12], *b2   = (const float*)d_in[13];
    const float *gn2w = (const float*)d_in[14], *gn2b = (const float*)d_in[15], *gn2s = (const float*)d_in[16];
    const float *w_l3 = (const float*)d_in[17], *w_r3 = (const float*)d_in[18];
    const float *att3 = (const float*)d_in[19], *b3   = (const float*)d_in[20];
    const float *gn3w = (const float*)d_in[21], *gn3b = (const float*)d_in[22], *gn3s = (const float*)d_in[23];
    const float *lw   = (const float*)d_in[24], *lb   = (const float*)d_in[25];

    char* ws = (char*)d_ws;
    size_t off = 0;
    auto alloc = [&](size_t bytes) -> void* {
        void* p = ws + off;
        off += (bytes + 255) & ~(size_t)255;
        return p;
    };
    __half* Ah  = (__half*)alloc((size_t)NN * 128 * 2);  // x_l fp16 (GEMM out, attn gather operand)
    __half* Xh  = (__half*)alloc((size_t)NN * 128 * 2);  // GEMM fp16 input (cast of x / gnnorm out)
    float*  B   = (float*)alloc((size_t)NN * 128 * 4);   // x_r / layer-out scratch
    float*  Cb  = (float*)alloc((size_t)NN * 64 * 4);    // h2 scratch
    float*  Af  = (float*)alloc((size_t)NN * 8 * 4);     // layer-3 final node features
    _Float16* Wf1 = (_Float16*)alloc((size_t)256 * 128 * 2);  // frag-ordered weights l1
    _Float16* Wf2 = (_Float16*)alloc((size_t)128 * 128 * 2);  // l2
    _Float16* Wf3 = (_Float16*)alloc((size_t)64 * 64 * 2);    // l3
    int* rowptr = (int*)alloc((size_t)(NN + 1) * 4);
    int* cursor = (int*)alloc((size_t)NN * 4);
    unsigned short* colsrc = (unsigned short*)alloc((size_t)ET * 2);
    int* bpos   = (int*)alloc((size_t)(NG + 1) * 4);
    int* cnt    = (int*)alloc((size_t)NG * 4);
    int* bsum   = (int*)alloc((size_t)NB * 4);
    int* boff   = (int*)alloc((size_t)NB * 4);
    char* zbase = ws + off;                              // everything below gets one memset
    int*   deg  = (int*)alloc((size_t)NN * 4);
    float* sum1 = (float*)alloc((size_t)NG * 128 * 4);
    float* sq1  = (float*)alloc((size_t)NG * 128 * 4);
    float* sum2 = (float*)alloc((size_t)NG * 64 * 4);
    float* sq2  = (float*)alloc((size_t)NG * 64 * 4);
    float* sum3 = (float*)alloc((size_t)NG * 8 * 4);
    float* sq3  = (float*)alloc((size_t)NG * 8 * 4);
    float* pool = (float*)alloc((size_t)NG * 8 * 4);
    size_t zbytes = (size_t)((ws + off) - zbase);
    (void)hipMemsetAsync(zbase, 0, zbytes, stream);

    int gE = (ET + 255) / 256;
    k_cast<<<(NN * 128 / 8 + 255) / 256, 256, 0, stream>>>(x, Xh);
    k_wprep_all<<<26, 256, 0, stream>>>(w_l1, w_r1, w_l2, w_r2, w_l3, w_r3, Wf1, Wf2, Wf3);
    k_count<<<gE, 256, 0, stream>>>(ei, deg);
    k_bounds<<<(NN + 255) / 256, 256, 0, stream>>>(batch, bpos);
    k_blksum<<<NB, 256, 0, stream>>>(deg, bsum);
    k_scanb<<<1, 256, 0, stream>>>(bsum, boff, bpos, cnt);
    k_scanc<<<NB, 256, 0, stream>>>(deg, boff, rowptr, cursor);
    k_scatter<<<gE, 256, 0, stream>>>(ei, cursor, colsrc);

    int gA4 = (NN * H * 4) / 256;            // attention grid, EP=4 -> 3125 blocks exact
    int gG  = (NN + 63) / 64;                // gn-reduce grid, 64 nodes/block
    int gD  = (NN + 63) / 64;                // dualgemm grid, 64 rows/block

    // ---- layer 1: 128 -> 4x32 concat -> 128
    k_dualgemm<128, 128><<<gD, 256, 0, stream>>>(Xh, Wf1, Ah, B);
    k_attn<32, 4, true><<<gA4, 256, 0, stream>>>(Ah, B, rowptr, colsrc, att1, b1, B);
    k_gnred<7><<<gG, 256, 0, stream>>>(B, batch, sum1, sq1);
    k_gnnorm<<<(NN * 128 + 255) / 256, 256, 0, stream>>>(B, batch, sum1, sq1, cnt, gn1w, gn1b, gn1s, 7, Xh);

    // ---- layer 2: 128 -> 4x16 concat -> 64
    k_dualgemm<128, 64><<<gD, 256, 0, stream>>>(Xh, Wf2, Ah, Cb);
    k_attn<16, 4, true><<<gA4, 256, 0, stream>>>(Ah, Cb, rowptr, colsrc, att2, b2, Cb);
    k_gnred<6><<<gG, 256, 0, stream>>>(Cb, batch, sum2, sq2);
    k_gnnorm<<<(NN * 64 + 255) / 256, 256, 0, stream>>>(Cb, batch, sum2, sq2, cnt, gn2w, gn2b, gn2s, 6, Xh);

    // ---- layer 3: 64 -> 4x8 mean -> 8
    k_dualgemm<64, 32><<<gD, 256, 0, stream>>>(Xh, Wf3, Ah, B);
    k_attn<8, 4, false><<<gA4, 256, 0, stream>>>(Ah, B, rowptr, colsrc, att3, nullptr, B);
    k_headmean<<<(NN * 8 + 255) / 256, 256, 0, stream>>>(B, b3, Af);
    k_gnred<3><<<gG, 256, 0, stream>>>(Af, batch, sum3, sq3);
    k_gnnorm<<<(NN * 8 + 255) / 256, 256, 0, stream>>>(Af, batch, sum3, sq3, cnt, gn3w, gn3b, gn3s, 3, nullptr);

    // ---- global mean pool + linear
    k_gnred<3><<<gG, 256, 0, stream>>>(Af, batch, pool, sq3);  // sq3 as throwaway sumsq
    k_final<<<1, 512, 0, stream>>>(pool, cnt, lw, lb, (float*)d_out);
}